// Round 1
// baseline (971.767 us; speedup 1.0000x reference)
//
#include <hip/hip_runtime.h>

#define B_    16
#define D_    256
#define H_    32
#define W_    32
#define SP    1024        // H_*W_
#define N_TOT 16384       // B_*SP
#define K_    8192
#define ZB    (D_*SP)     // floats per batch in z (262144)

#define MT 128            // rows per block
#define CT 128            // codes per chunk
#define DT 32             // d per LDS stage
#define NSTRIPE 8
#define CPS (K_/NSTRIPE)  // 1024 codes per stripe
#define ES (CT+4)         // padded LDS row stride for e tile

// ---------------- ws layout (in floats) ----------------
// [0, 8192)             enorm  (||e_k||^2)
// [8192, 270336)        zpart  (16 x 16384 partial z-norms)
// [270336, 286720)      znorm  (||z_n||^2)
// [286720, 417792)      pvals  (16384 x 8 stripe-min values)
// [417792, 548864)      pidx   (int, 16384 x 8 stripe argmins)
// [548864, 565248)      fidx   (int, final argmin per row)

__global__ __launch_bounds__(256)
void enorm_kernel(const float* __restrict__ emb, float* __restrict__ enorm) {
    int t = threadIdx.x;
    int k = blockIdx.x * 4 + (t >> 6);
    int l = t & 63;
    float4 v = *(const float4*)(emb + (size_t)k * D_ + l * 4);
    float sum = v.x*v.x + v.y*v.y + v.z*v.z + v.w*v.w;
    for (int m = 1; m < 64; m <<= 1) sum += __shfl_xor(sum, m, 64);
    if (l == 0) enorm[k] = sum;
}

__global__ __launch_bounds__(256)
void zpart_kernel(const float* __restrict__ z, float* __restrict__ zpart) {
    int bx = blockIdx.x;          // b*16 + dc
    int b  = bx >> 4;
    int dc = bx & 15;
    int t  = threadIdx.x;
#pragma unroll
    for (int i = 0; i < 4; ++i) {
        int s = t + i * 256;
        float sum = 0.f;
#pragma unroll
        for (int dd = 0; dd < 16; ++dd) {
            float v = z[(size_t)b * ZB + (size_t)(dc * 16 + dd) * SP + s];
            sum += v * v;
        }
        zpart[(size_t)dc * N_TOT + b * SP + s] = sum;
    }
}

__global__ __launch_bounds__(256)
void znorm_kernel(const float* __restrict__ zpart, float* __restrict__ znorm) {
    int n = blockIdx.x * 256 + threadIdx.x;
    float sum = 0.f;
#pragma unroll
    for (int dc = 0; dc < 16; ++dc) sum += zpart[(size_t)dc * N_TOT + n];
    znorm[n] = sum;
}

// Fused fp32 GEMM + running argmin over a 1024-code stripe.
// Replicates np rounding: s = fl( fl(zn + ek2) - fl(2*dot) ).
__global__ __launch_bounds__(256)
void gemm_argmin(const float* __restrict__ z, const float* __restrict__ emb,
                 const float* __restrict__ enorm, const float* __restrict__ znorm,
                 float* __restrict__ pvals, int* __restrict__ pidx) {
    __shared__ float zs[DT][MT];   // 16 KB
    __shared__ float es[DT][ES];   // ~16.9 KB
    const int t = threadIdx.x;
    const int bx = blockIdx.x;
    const int stripe = bx & (NSTRIPE - 1);
    const int rb = bx >> 3;            // 0..127
    const int n0 = rb * MT;
    const int b  = n0 / SP;
    const int s0 = n0 % SP;            // multiple of 128
    const float* zb = z + (size_t)b * ZB + s0;

    const int tc = t & 15;             // code group
    const int tr = t >> 4;             // row group

    float zn[8];
#pragma unroll
    for (int i = 0; i < 8; ++i) zn[i] = znorm[n0 + tr * 8 + i];

    float best[8];
    int bidx[8];
#pragma unroll
    for (int i = 0; i < 8; ++i) { best[i] = 3.4e38f; bidx[i] = 0; }

    for (int cc = 0; cc < CPS / CT; ++cc) {
        const int c0 = stripe * CPS + cc * CT;
        float acc[8][8];
#pragma unroll
        for (int i = 0; i < 8; ++i)
#pragma unroll
            for (int j = 0; j < 8; ++j) acc[i][j] = 0.f;

        for (int dc = 0; dc < D_ / DT; ++dc) {
            const int d0 = dc * DT;
            __syncthreads();
            // stage z: DT x MT (z is [d][spatial]-contiguous in NCHW)
#pragma unroll
            for (int i = 0; i < 4; ++i) {
                int p  = t + i * 256;          // 0..1023 float4 slots
                int d  = p >> 5;               // 32 float4 per d row
                int rq = p & 31;
                float4 v = *(const float4*)(zb + (size_t)(d0 + d) * SP + rq * 4);
                *(float4*)&zs[d][rq * 4] = v;
            }
            // stage e: read along d (contiguous), scatter-transpose into [d][c]
#pragma unroll
            for (int i = 0; i < 4; ++i) {
                int p  = t + i * 256;
                int c  = p >> 3;               // 8 dq-quads per code
                int dq = p & 7;
                float4 v = *(const float4*)(emb + (size_t)(c0 + c) * D_ + d0 + dq * 4);
                es[dq * 4 + 0][c] = v.x;
                es[dq * 4 + 1][c] = v.y;
                es[dq * 4 + 2][c] = v.z;
                es[dq * 4 + 3][c] = v.w;
            }
            __syncthreads();
#pragma unroll 8
            for (int d = 0; d < DT; ++d) {
                float zr[8], ec[8];
                *(float4*)&zr[0] = *(const float4*)&zs[d][tr * 8];
                *(float4*)&zr[4] = *(const float4*)&zs[d][tr * 8 + 4];
                *(float4*)&ec[0] = *(const float4*)&es[d][tc * 8];
                *(float4*)&ec[4] = *(const float4*)&es[d][tc * 8 + 4];
#pragma unroll
                for (int i = 0; i < 8; ++i)
#pragma unroll
                    for (int j = 0; j < 8; ++j)
                        acc[i][j] = fmaf(zr[i], ec[j], acc[i][j]);
            }
        }
        // epilogue: replicate reference rounding, update running argmin
        float ek[8];
#pragma unroll
        for (int j = 0; j < 8; ++j) ek[j] = enorm[c0 + tc * 8 + j];
#pragma unroll
        for (int i = 0; i < 8; ++i) {
#pragma unroll
            for (int j = 0; j < 8; ++j) {
                float s = (zn[i] + ek[j]) - 2.0f * acc[i][j];
                int code = c0 + tc * 8 + j;
                if (s < best[i] || (s == best[i] && code < bidx[i])) {
                    best[i] = s; bidx[i] = code;
                }
            }
        }
    }
    // reduce across the 16 code-group lanes (same tr)
#pragma unroll
    for (int i = 0; i < 8; ++i) {
        float v = best[i]; int ix = bidx[i];
        for (int m = 1; m < 16; m <<= 1) {
            float ov = __shfl_xor(v, m, 64);
            int   oi = __shfl_xor(ix, m, 64);
            if (ov < v || (ov == v && oi < ix)) { v = ov; ix = oi; }
        }
        if (tc == 0) {
            int n = n0 + tr * 8 + i;
            pvals[n * NSTRIPE + stripe] = v;
            pidx [n * NSTRIPE + stripe] = ix;
        }
    }
}

__global__ __launch_bounds__(256)
void reduce_rows(const float* __restrict__ pvals, const int* __restrict__ pidx,
                 int* __restrict__ fidx, float* __restrict__ out_idx) {
    int n = blockIdx.x * 256 + threadIdx.x;
    float bv = 3.4e38f; int bi = 0;
#pragma unroll
    for (int s = 0; s < NSTRIPE; ++s) {
        float v = pvals[n * NSTRIPE + s];
        int  ix = pidx [n * NSTRIPE + s];
        if (v < bv || (v == bv && ix < bi)) { bv = v; bi = ix; }
    }
    fidx[n] = bi;
    out_idx[n] = (float)bi;
}

__global__ __launch_bounds__(256)
void output_kernel(const float* __restrict__ z, const float* __restrict__ emb,
                   const int* __restrict__ fidx, float* __restrict__ out,
                   float* __restrict__ loss) {
    const int bx = blockIdx.x;     // b*256 + d
    const int b  = bx >> 8;
    const int d  = bx & 255;
    const int t  = threadIdx.x;
    float lsum = 0.f;
#pragma unroll
    for (int i = 0; i < 4; ++i) {
        int s = t + i * 256;
        int n = b * SP + s;
        int idx = fidx[n];
        float q  = emb[(size_t)idx * D_ + d];
        float zv = z[(size_t)bx * SP + s];
        float diff = q - zv;                // fl(q - z)
        float o = zv + diff;                // straight-through: fl(z + fl(q - z))
        out[(size_t)bx * SP + s] = o;
        lsum += diff * diff;
    }
    __shared__ float red[4];
    for (int m = 1; m < 64; m <<= 1) lsum += __shfl_xor(lsum, m, 64);
    if ((t & 63) == 0) red[t >> 6] = lsum;
    __syncthreads();
    if (t == 0) {
        float tot = (red[0] + red[1] + red[2] + red[3])
                    * (1.25f / (float)(B_ * SP * D_));
        atomicAdd(loss, tot);
    }
}

extern "C" void kernel_launch(void* const* d_in, const int* in_sizes, int n_in,
                              void* d_out, int out_size, void* d_ws, size_t ws_size,
                              hipStream_t stream) {
    const float* z   = (const float*)d_in[0];
    const float* emb = (const float*)d_in[1];
    float* out = (float*)d_out;

    float* w      = (float*)d_ws;
    float* enorm  = w;
    float* zpart  = w + 8192;
    float* znorm  = w + 270336;
    float* pvals  = w + 286720;
    int*   pidx   = (int*)(w + 417792);
    int*   fidx   = (int*)(w + 548864);

    float* out0     = out;                  // [B,D,H,W] quantized_st
    float* out_loss = out + (size_t)B_ * D_ * SP;      // scalar
    float* out_idx  = out_loss + 1;         // [B,H,W] indices as float

    enorm_kernel<<<K_ / 4, 256, 0, stream>>>(emb, enorm);
    zpart_kernel<<<B_ * 16, 256, 0, stream>>>(z, zpart);
    znorm_kernel<<<N_TOT / 256, 256, 0, stream>>>(zpart, znorm);
    gemm_argmin<<<(N_TOT / MT) * NSTRIPE, 256, 0, stream>>>(z, emb, enorm, znorm,
                                                            pvals, pidx);
    reduce_rows<<<N_TOT / 256, 256, 0, stream>>>(pvals, pidx, fidx, out_idx);
    hipMemsetAsync(out_loss, 0, sizeof(float), stream);
    output_kernel<<<B_ * D_, 256, 0, stream>>>(z, emb, fidx, out0, out_loss);
}

// Round 2
// 428.141 us; speedup vs baseline: 2.2697x; 2.2697x over previous
//
#include <hip/hip_runtime.h>

#define B_    16
#define D_    256
#define H_    32
#define W_    32
#define SP    1024        // H_*W_
#define N_TOT 16384       // B_*SP
#define K_    8192
#define ZB    (D_*SP)     // floats per batch in z (262144)

typedef __attribute__((ext_vector_type(8))) short bf16x8;
typedef __attribute__((ext_vector_type(4))) float f32x4;

#define GLOAD_LDS16(g, l) \
    __builtin_amdgcn_global_load_lds((const __attribute__((address_space(1))) void*)(g), \
                                     (__attribute__((address_space(3))) void*)(l), 16, 0, 0)

__device__ __forceinline__ unsigned short f2bf(float f) {
    unsigned u = __float_as_uint(f);
    u += 0x7FFFu + ((u >> 16) & 1u);          // RNE
    return (unsigned short)(u >> 16);
}

// ======================= shared pre-passes =======================

__global__ __launch_bounds__(256)
void enorm_kernel(const float* __restrict__ emb, float* __restrict__ enorm) {
    int t = threadIdx.x;
    int k = blockIdx.x * 4 + (t >> 6);
    int l = t & 63;
    float4 v = *(const float4*)(emb + (size_t)k * D_ + l * 4);
    float sum = v.x*v.x + v.y*v.y + v.z*v.z + v.w*v.w;
    for (int m = 1; m < 64; m <<= 1) sum += __shfl_xor(sum, m, 64);
    if (l == 0) enorm[k] = sum;
}

__global__ __launch_bounds__(256)
void zpart_kernel(const float* __restrict__ z, float* __restrict__ zpart) {
    int bx = blockIdx.x;          // b*16 + dc
    int b  = bx >> 4;
    int dc = bx & 15;
    int t  = threadIdx.x;
#pragma unroll
    for (int i = 0; i < 4; ++i) {
        int s = t + i * 256;
        float sum = 0.f;
#pragma unroll
        for (int dd = 0; dd < 16; ++dd) {
            float v = z[(size_t)b * ZB + (size_t)(dc * 16 + dd) * SP + s];
            sum += v * v;
        }
        zpart[(size_t)dc * N_TOT + b * SP + s] = sum;
    }
}

__global__ __launch_bounds__(256)
void znorm_kernel(const float* __restrict__ zpart, float* __restrict__ znorm) {
    int n = blockIdx.x * 256 + threadIdx.x;
    float sum = 0.f;
#pragma unroll
    for (int dc = 0; dc < 16; ++dc) sum += zpart[(size_t)dc * N_TOT + n];
    znorm[n] = sum;
}

// ======================= fast path: bf16 conversion =======================
// ET2 layout: [dc=8][k=8192][32 bf16]  (d-chunked, row-contiguous 64B)
// ZT2 layout: [dc=8][n=16384][32 bf16]

__global__ __launch_bounds__(256)
void cvt_e(const float* __restrict__ emb, short* __restrict__ ET2) {
    int tg  = blockIdx.x * 256 + threadIdx.x;   // 0..262143
    int dc  = tg >> 15;
    int rem = tg & 32767;
    int k   = rem >> 2;
    int g   = rem & 3;
    const float* src = emb + (size_t)k * D_ + dc * 32 + g * 8;
    float4 u = *(const float4*)src;
    float4 w = *(const float4*)(src + 4);
    bf16x8 v;
    v[0]=(short)f2bf(u.x); v[1]=(short)f2bf(u.y); v[2]=(short)f2bf(u.z); v[3]=(short)f2bf(u.w);
    v[4]=(short)f2bf(w.x); v[5]=(short)f2bf(w.y); v[6]=(short)f2bf(w.z); v[7]=(short)f2bf(w.w);
    *(bf16x8*)(ET2 + ((size_t)dc * K_ + k) * 32 + g * 8) = v;
}

__global__ __launch_bounds__(256)
void cvt_z(const float* __restrict__ z, short* __restrict__ ZT2) {
    __shared__ float tr[32][260];               // padded: stride 260 (bank-friendly)
    int bx = blockIdx.x;                        // dc*64 + ntile
    int dc = bx >> 6;
    int nt = bx & 63;
    int n0 = nt * 256;
    int b  = n0 >> 10;
    int s0 = n0 & 1023;
    int t  = threadIdx.x;
#pragma unroll
    for (int i = 0; i < 8; ++i) {
        int flat = t + i * 256;                 // 0..2047 float4 slots
        int d = flat >> 6;
        int q = flat & 63;
        float4 v = *(const float4*)(z + (size_t)b * ZB + (size_t)(dc * 32 + d) * SP + s0 + q * 4);
        tr[d][q*4+0] = v.x; tr[d][q*4+1] = v.y; tr[d][q*4+2] = v.z; tr[d][q*4+3] = v.w;
    }
    __syncthreads();
    short* dst = ZT2 + ((size_t)dc * N_TOT + n0 + t) * 32;
#pragma unroll
    for (int j = 0; j < 4; ++j) {
        bf16x8 vv;
#pragma unroll
        for (int e = 0; e < 8; ++e) vv[e] = (short)f2bf(tr[j * 8 + e][t]);
        *(bf16x8*)(dst + j * 8) = vv;
    }
}

// ======================= fast path: MFMA GEMM + top-2 argmin =======================
// Block: 128 rows x 1024-code stripe (8 chunks of 128 codes), 4 waves in 2x2.
// A operand = e-codes (M), B operand = z-rows (N). s~ = enorm[code] - 2*dot
// (znorm dropped: constant per row, irrelevant for per-row argmin).
// Output: per (row, stripe) lex-top-2 (val,code) -> pv2[n*8+stripe] as float4.

__global__ __launch_bounds__(256)
void mfma_argmin(const short* __restrict__ ET2, const short* __restrict__ ZT2,
                 const float* __restrict__ enorm, float4* __restrict__ pv2) {
    __shared__ char smem[16384];
    short* es = (short*)smem;                   // [128 codes][32 d] bf16, 8KB
    short* zs = (short*)(smem + 8192);          // [128 rows ][32 d] bf16, 8KB
    float4* mbuf = (float4*)smem;               // overlay after loop: [2][128]

    const int t    = threadIdx.x;
    const int wid  = t >> 6, lane = t & 63;
    const int quad = lane >> 4, l16 = lane & 15;
    const int wm   = wid >> 1, wn = wid & 1;    // wave tile: codes wm*64, rows wn*64
    const int stripe = blockIdx.x & 7;
    const int n0     = (blockIdx.x >> 3) * 128;

    float v1[4], v2[4]; int c1[4], c2[4];       // per fj (row frag): running top-2
#pragma unroll
    for (int fj = 0; fj < 4; ++fj) { v1[fj] = 3.4e38f; v2[fj] = 3.4e38f;
                                     c1[fj] = 0x7fffffff; c2[fj] = 0x7fffffff; }

    for (int cc = 0; cc < 8; ++cc) {
        const int c0 = stripe * 1024 + cc * 128;
        f32x4 acc[4][4];
#pragma unroll
        for (int fi = 0; fi < 4; ++fi)
#pragma unroll
            for (int fj = 0; fj < 4; ++fj) acc[fi][fj] = (f32x4){0.f, 0.f, 0.f, 0.f};

        for (int dc = 0; dc < 8; ++dc) {
            __syncthreads();                    // LDS reuse fence
            const char* ge = (const char*)(ET2 + ((size_t)dc * K_    + c0) * 32);
            const char* gz = (const char*)(ZT2 + ((size_t)dc * N_TOT + n0) * 32);
#pragma unroll
            for (int j = 0; j < 2; ++j) {
                int off = wid * 2048 + j * 1024;            // bytes within 8KB tile
                GLOAD_LDS16(ge + off + lane * 16, smem + off);
                GLOAD_LDS16(gz + off + lane * 16, smem + 8192 + off);
            }
            __syncthreads();                    // vmcnt(0) drained by compiler

            bf16x8 af[4], bfr[4];
            const short* ea = es + (wm * 64 + l16) * 32 + quad * 8;
            const short* zb = zs + (wn * 64 + l16) * 32 + quad * 8;
#pragma unroll
            for (int fi = 0; fi < 4; ++fi) af[fi]  = *(const bf16x8*)(ea + fi * 512);
#pragma unroll
            for (int fj = 0; fj < 4; ++fj) bfr[fj] = *(const bf16x8*)(zb + fj * 512);
#pragma unroll
            for (int fi = 0; fi < 4; ++fi)
#pragma unroll
                for (int fj = 0; fj < 4; ++fj)
                    acc[fi][fj] = __builtin_amdgcn_mfma_f32_16x16x32_bf16(
                        af[fi], bfr[fj], acc[fi][fj], 0, 0, 0);
        }

        // epilogue: s~ = ek - 2*acc; codes ascend per (lane,fj) so strict '<'
        // keeps the lowest index on value ties.
#pragma unroll
        for (int fi = 0; fi < 4; ++fi) {
            const int cb = c0 + wm * 64 + fi * 16 + quad * 4;
            float4 ek = *(const float4*)(enorm + cb);
            float ekv[4] = {ek.x, ek.y, ek.z, ek.w};
#pragma unroll
            for (int fj = 0; fj < 4; ++fj) {
                float av[4] = {acc[fi][fj].x, acc[fi][fj].y, acc[fi][fj].z, acc[fi][fj].w};
#pragma unroll
                for (int r = 0; r < 4; ++r) {
                    float s = fmaf(-2.f, av[r], ekv[r]);
                    int code = cb + r;
                    if (s < v1[fj]) { v2[fj] = v1[fj]; c2[fj] = c1[fj];
                                      v1[fj] = s;      c1[fj] = code; }
                    else if (s < v2[fj]) { v2[fj] = s; c2[fj] = code; }
                }
            }
        }
    }

    __syncthreads();                            // all LDS frag reads complete
    // cross-quad lex merge (lanes ^16, ^32 hold same row, different codes)
#pragma unroll
    for (int fj = 0; fj < 4; ++fj) {
        float a1 = v1[fj], a2 = v2[fj]; int b1 = c1[fj], b2 = c2[fj];
#pragma unroll
        for (int m = 16; m <= 32; m <<= 1) {
            float o1 = __shfl_xor(a1, m, 64); int p1 = __shfl_xor(b1, m, 64);
            float o2 = __shfl_xor(a2, m, 64); int p2 = __shfl_xor(b2, m, 64);
            bool oLt = (o1 < a1) || (o1 == a1 && p1 < b1);
            float w1 = oLt ? o1 : a1; int x1 = oLt ? p1 : b1;
            float L1 = oLt ? a1 : o1; int y1 = oLt ? b1 : p1;   // loser of firsts
            float s1 = oLt ? o2 : a2; int u1 = oLt ? p2 : b2;   // winner's second
            bool sLt = (s1 < L1) || (s1 == L1 && u1 < y1);
            a1 = w1; b1 = x1;
            a2 = sLt ? s1 : L1; b2 = sLt ? u1 : y1;
        }
        if (quad == 0) {
            int row = wn * 64 + fj * 16 + l16;
            mbuf[wm * 128 + row] = make_float4(a1, __int_as_float(b1),
                                               a2, __int_as_float(b2));
        }
    }
    __syncthreads();
    if (t < 128) {                              // merge the two code-halves
        float4 P = mbuf[t], Q = mbuf[128 + t];
        float a1 = P.x, a2 = P.z; int b1 = __float_as_int(P.y), b2 = __float_as_int(P.w);
        float o1 = Q.x, o2 = Q.z; int p1 = __float_as_int(Q.y), p2 = __float_as_int(Q.w);
        bool oLt = (o1 < a1) || (o1 == a1 && p1 < b1);
        float w1 = oLt ? o1 : a1; int x1 = oLt ? p1 : b1;
        float L1 = oLt ? a1 : o1; int y1 = oLt ? b1 : p1;
        float s1 = oLt ? o2 : a2; int u1 = oLt ? p2 : b2;
        bool sLt = (s1 < L1) || (s1 == L1 && u1 < y1);
        float r2 = sLt ? s1 : L1; int q2 = sLt ? u1 : y1;
        pv2[(size_t)(n0 + t) * 8 + stripe] = make_float4(w1, __int_as_float(x1),
                                                         r2, __int_as_float(q2));
    }
}

// ======================= fast path: window reduce + exact recheck =======================
#define DELTA 1.25e-4f

__global__ __launch_bounds__(256)
void reduce_exact(const float4* __restrict__ pv2, const float* __restrict__ znorm,
                  const float* __restrict__ enorm, const float* __restrict__ z,
                  const float* __restrict__ emb, int* __restrict__ fidx,
                  float* __restrict__ out_idx) {
    int n = blockIdx.x * 256 + threadIdx.x;
    float vals[16]; int cods[16];
#pragma unroll
    for (int s = 0; s < 8; ++s) {
        float4 p = pv2[(size_t)n * 8 + s];
        vals[s*2]   = p.x; cods[s*2]   = __float_as_int(p.y);
        vals[s*2+1] = p.z; cods[s*2+1] = __float_as_int(p.w);
    }
    float bv = vals[0]; int bc = cods[0];
#pragma unroll
    for (int i = 1; i < 16; ++i)
        if (vals[i] < bv || (vals[i] == bv && cods[i] < bc)) { bv = vals[i]; bc = cods[i]; }
    int cnt = 0;
#pragma unroll
    for (int i = 0; i < 16; ++i) cnt += (vals[i] <= bv + DELTA) ? 1 : 0;
    if (cnt > 1) {
        // exact fp32 recheck, replicating the verified round-1 summation order:
        // sequential fmaf d=0..255, s = (zn + ek) - 2*dot, lowest-index tie-break.
        int b = n >> 10, sp = n & 1023;
        const float* zr = z + (size_t)b * ZB + sp;
        float zn = znorm[n];
        float bs = 3.4e38f; int bcc = 0x7fffffff;
#pragma unroll
        for (int i = 0; i < 16; ++i) {
            if (vals[i] <= bv + DELTA) {
                int c = cods[i];
                const float* er = emb + (size_t)c * D_;
                float dot = 0.f;
                for (int d = 0; d < D_; ++d) dot = fmaf(zr[(size_t)d * SP], er[d], dot);
                float s = (zn + enorm[c]) - 2.f * dot;
                if (s < bs || (s == bs && c < bcc)) { bs = s; bcc = c; }
            }
        }
        bc = bcc;
    }
    fidx[n] = bc;
    out_idx[n] = (float)bc;
}

// ======================= fallback path (round-1, proven) =======================
#define MT 128
#define CT 128
#define DT 32
#define NSTRIPE 8
#define CPS (K_/NSTRIPE)
#define ES (CT+4)

__global__ __launch_bounds__(256)
void gemm_argmin(const float* __restrict__ z, const float* __restrict__ emb,
                 const float* __restrict__ enorm, const float* __restrict__ znorm,
                 float* __restrict__ pvals, int* __restrict__ pidx) {
    __shared__ float zsm[DT][MT];
    __shared__ float esm[DT][ES];
    const int t = threadIdx.x;
    const int bx = blockIdx.x;
    const int stripe = bx & (NSTRIPE - 1);
    const int rb = bx >> 3;
    const int n0 = rb * MT;
    const int b  = n0 / SP;
    const int s0 = n0 % SP;
    const float* zb = z + (size_t)b * ZB + s0;
    const int tc = t & 15;
    const int tr = t >> 4;
    float zn[8];
#pragma unroll
    for (int i = 0; i < 8; ++i) zn[i] = znorm[n0 + tr * 8 + i];
    float best[8]; int bidx[8];
#pragma unroll
    for (int i = 0; i < 8; ++i) { best[i] = 3.4e38f; bidx[i] = 0; }
    for (int cc = 0; cc < CPS / CT; ++cc) {
        const int c0 = stripe * CPS + cc * CT;
        float acc[8][8];
#pragma unroll
        for (int i = 0; i < 8; ++i)
#pragma unroll
            for (int j = 0; j < 8; ++j) acc[i][j] = 0.f;
        for (int dc = 0; dc < D_ / DT; ++dc) {
            const int d0 = dc * DT;
            __syncthreads();
#pragma unroll
            for (int i = 0; i < 4; ++i) {
                int p  = t + i * 256;
                int d  = p >> 5;
                int rq = p & 31;
                float4 v = *(const float4*)(zb + (size_t)(d0 + d) * SP + rq * 4);
                *(float4*)&zsm[d][rq * 4] = v;
            }
#pragma unroll
            for (int i = 0; i < 4; ++i) {
                int p  = t + i * 256;
                int c  = p >> 3;
                int dq = p & 7;
                float4 v = *(const float4*)(emb + (size_t)(c0 + c) * D_ + d0 + dq * 4);
                esm[dq * 4 + 0][c] = v.x;
                esm[dq * 4 + 1][c] = v.y;
                esm[dq * 4 + 2][c] = v.z;
                esm[dq * 4 + 3][c] = v.w;
            }
            __syncthreads();
#pragma unroll 8
            for (int d = 0; d < DT; ++d) {
                float zr[8], ec[8];
                *(float4*)&zr[0] = *(const float4*)&zsm[d][tr * 8];
                *(float4*)&zr[4] = *(const float4*)&zsm[d][tr * 8 + 4];
                *(float4*)&ec[0] = *(const float4*)&esm[d][tc * 8];
                *(float4*)&ec[4] = *(const float4*)&esm[d][tc * 8 + 4];
#pragma unroll
                for (int i = 0; i < 8; ++i)
#pragma unroll
                    for (int j = 0; j < 8; ++j)
                        acc[i][j] = fmaf(zr[i], ec[j], acc[i][j]);
            }
        }
        float ek[8];
#pragma unroll
        for (int j = 0; j < 8; ++j) ek[j] = enorm[c0 + tc * 8 + j];
#pragma unroll
        for (int i = 0; i < 8; ++i) {
#pragma unroll
            for (int j = 0; j < 8; ++j) {
                float s = (zn[i] + ek[j]) - 2.0f * acc[i][j];
                int code = c0 + tc * 8 + j;
                if (s < best[i] || (s == best[i] && code < bidx[i])) {
                    best[i] = s; bidx[i] = code;
                }
            }
        }
    }
#pragma unroll
    for (int i = 0; i < 8; ++i) {
        float v = best[i]; int ix = bidx[i];
        for (int m = 1; m < 16; m <<= 1) {
            float ov = __shfl_xor(v, m, 64);
            int   oi = __shfl_xor(ix, m, 64);
            if (ov < v || (ov == v && oi < ix)) { v = ov; ix = oi; }
        }
        if (tc == 0) {
            int n = n0 + tr * 8 + i;
            pvals[n * NSTRIPE + stripe] = v;
            pidx [n * NSTRIPE + stripe] = ix;
        }
    }
}

__global__ __launch_bounds__(256)
void reduce_rows(const float* __restrict__ pvals, const int* __restrict__ pidx,
                 int* __restrict__ fidx, float* __restrict__ out_idx) {
    int n = blockIdx.x * 256 + threadIdx.x;
    float bv = 3.4e38f; int bi = 0;
#pragma unroll
    for (int s = 0; s < NSTRIPE; ++s) {
        float v = pvals[n * NSTRIPE + s];
        int  ix = pidx [n * NSTRIPE + s];
        if (v < bv || (v == bv && ix < bi)) { bv = v; bi = ix; }
    }
    fidx[n] = bi;
    out_idx[n] = (float)bi;
}

// ======================= output / loss =======================

__global__ __launch_bounds__(256)
void output_kernel(const float* __restrict__ z, const float* __restrict__ emb,
                   const int* __restrict__ fidx, float* __restrict__ out,
                   float* __restrict__ loss) {
    const int bx = blockIdx.x;     // b*256 + d
    const int b  = bx >> 8;
    const int d  = bx & 255;
    const int t  = threadIdx.x;
    float lsum = 0.f;
#pragma unroll
    for (int i = 0; i < 4; ++i) {
        int s = t + i * 256;
        int n = b * SP + s;
        int idx = fidx[n];
        float q  = emb[(size_t)idx * D_ + d];
        float zv = z[(size_t)bx * SP + s];
        float diff = q - zv;
        float o = zv + diff;
        out[(size_t)bx * SP + s] = o;
        lsum += diff * diff;
    }
    __shared__ float red[4];
    for (int m = 1; m < 64; m <<= 1) lsum += __shfl_xor(lsum, m, 64);
    if ((t & 63) == 0) red[t >> 6] = lsum;
    __syncthreads();
    if (t == 0) {
        float tot = (red[0] + red[1] + red[2] + red[3])
                    * (1.25f / (float)(B_ * SP * D_));
        atomicAdd(loss, tot);
    }
}

// ======================= launch =======================
// fast-path ws layout (floats):
//   enorm  [0, 8192)           zpart [8192, 270336)      znorm [270336, 286720)
//   pv2    [286720, 811008)    fidx  [811008, 827392)
//   ET2(bf16) [827392, 1875968)   ZT2(bf16) [1875968, 3973120)
// NEED = 3973120*4 = 15,892,480 bytes. Fallback (round-1 layout) if ws smaller.

extern "C" void kernel_launch(void* const* d_in, const int* in_sizes, int n_in,
                              void* d_out, int out_size, void* d_ws, size_t ws_size,
                              hipStream_t stream) {
    const float* z   = (const float*)d_in[0];
    const float* emb = (const float*)d_in[1];
    float* out = (float*)d_out;
    float* w   = (float*)d_ws;

    float* enorm = w;
    float* zpart = w + 8192;
    float* znorm = w + 270336;

    float* out0     = out;
    float* out_loss = out + (size_t)B_ * D_ * SP;
    float* out_idx  = out_loss + 1;

    enorm_kernel<<<K_ / 4, 256, 0, stream>>>(emb, enorm);
    zpart_kernel<<<B_ * 16, 256, 0, stream>>>(z, zpart);
    znorm_kernel<<<N_TOT / 256, 256, 0, stream>>>(zpart, znorm);

    const size_t NEED = 3973120ULL * 4ULL;
    int* fidx;
    if (ws_size >= NEED) {
        float4* pv2 = (float4*)(w + 286720);
        fidx        = (int*)(w + 811008);
        short* ET2  = (short*)(w + 827392);
        short* ZT2  = (short*)(w + 1875968);
        cvt_e<<<1024, 256, 0, stream>>>(emb, ET2);
        cvt_z<<<512, 256, 0, stream>>>(z, ZT2);
        mfma_argmin<<<(N_TOT / 128) * 8, 256, 0, stream>>>(ET2, ZT2, enorm, pv2);
        reduce_exact<<<N_TOT / 256, 256, 0, stream>>>(pv2, znorm, enorm, z, emb,
                                                      fidx, out_idx);
    } else {
        float* pvals = w + 286720;
        int*   pidx  = (int*)(w + 417792);
        fidx         = (int*)(w + 548864);
        gemm_argmin<<<(N_TOT / MT) * NSTRIPE, 256, 0, stream>>>(z, emb, enorm, znorm,
                                                                pvals, pidx);
        reduce_rows<<<N_TOT / 256, 256, 0, stream>>>(pvals, pidx, fidx, out_idx);
    }

    hipMemsetAsync(out_loss, 0, sizeof(float), stream);
    output_kernel<<<B_ * D_, 256, 0, stream>>>(z, emb, fidx, out0, out_loss);
}

// Round 3
// 366.830 us; speedup vs baseline: 2.6491x; 1.1671x over previous
//
#include <hip/hip_runtime.h>

#define B_    16
#define D_    256
#define H_    32
#define W_    32
#define SP    1024        // H_*W_
#define N_TOT 16384       // B_*SP
#define K_    8192
#define ZB    (D_*SP)     // floats per batch in z

#define BIAS_  0.03125f
#define DELTA_ 2.5e-4f

typedef __attribute__((ext_vector_type(8))) short bf16x8;
typedef __attribute__((ext_vector_type(4))) float f32x4;

#define GLOAD_LDS16(g, l) \
    __builtin_amdgcn_global_load_lds((const __attribute__((address_space(1))) void*)(g), \
                                     (__attribute__((address_space(3))) void*)(l), 16, 0, 0)

__device__ __forceinline__ unsigned short f2bf(float f) {
    unsigned u = __float_as_uint(f);
    u += 0x7FFFu + ((u >> 16) & 1u);          // RNE
    return (unsigned short)(u >> 16);
}

// merge two sorted pairs (a1<=a2), (b1<=b2) -> top-2 in (a1,a2). u32 lex keys.
__device__ __forceinline__ void merge2(unsigned &a1, unsigned &a2,
                                       unsigned b1, unsigned b2) {
    unsigned m1  = min(a1, b1);
    unsigned hi  = max(a1, b1);
    unsigned sel = (a1 < b1) ? a2 : b2;
    a2 = min(hi, sel);
    a1 = m1;
}

// ======================= pre-passes =======================

__global__ __launch_bounds__(256)
void enorm_kernel(const float* __restrict__ emb, float* __restrict__ enorm,
                  float* __restrict__ enormB) {
    int t = threadIdx.x;
    int k = blockIdx.x * 4 + (t >> 6);
    int l = t & 63;
    float4 v = *(const float4*)(emb + (size_t)k * D_ + l * 4);
    float sum = v.x*v.x + v.y*v.y + v.z*v.z + v.w*v.w;
    for (int m = 1; m < 64; m <<= 1) sum += __shfl_xor(sum, m, 64);
    if (l == 0) { enorm[k] = sum; enormB[k] = sum + BIAS_; }
}

// keep round-1/2's verified zn summation structure exactly (16 chunks of 16)
__global__ __launch_bounds__(256)
void zpart_kernel(const float* __restrict__ z, float* __restrict__ zpart) {
    int bx = blockIdx.x;          // b*16 + dc
    int b  = bx >> 4;
    int dc = bx & 15;
    int t  = threadIdx.x;
#pragma unroll
    for (int i = 0; i < 4; ++i) {
        int s = t + i * 256;
        float sum = 0.f;
#pragma unroll
        for (int dd = 0; dd < 16; ++dd) {
            float v = z[(size_t)b * ZB + (size_t)(dc * 16 + dd) * SP + s];
            sum += v * v;
        }
        zpart[(size_t)dc * N_TOT + b * SP + s] = sum;
    }
}

__global__ __launch_bounds__(256)
void znorm_kernel(const float* __restrict__ zpart, float* __restrict__ znorm) {
    int n = blockIdx.x * 256 + threadIdx.x;
    float sum = 0.f;
#pragma unroll
    for (int dc = 0; dc < 16; ++dc) sum += zpart[(size_t)dc * N_TOT + n];
    znorm[n] = sum;
}

// ======================= bf16 conversion (swizzled layouts) =======================
// ET3: [dcb=4][k=8192][64 bf16] rows of 128B; 16B chunk c stored at c^(k&7)
// ZT3: [dcb=4][n=16384][64 bf16] same swizzle by (n&7)

__global__ __launch_bounds__(256)
void cvt_e(const float* __restrict__ emb, short* __restrict__ ET3) {
    int tid = blockIdx.x * 256 + threadIdx.x;   // 0..262143
    int k   = tid >> 5;
    int dcb = (tid >> 3) & 3;
    int c   = tid & 7;
    const float* src = emb + (size_t)k * D_ + dcb * 64 + c * 8;
    float4 u = *(const float4*)src;
    float4 w = *(const float4*)(src + 4);
    bf16x8 v;
    v[0]=(short)f2bf(u.x); v[1]=(short)f2bf(u.y); v[2]=(short)f2bf(u.z); v[3]=(short)f2bf(u.w);
    v[4]=(short)f2bf(w.x); v[5]=(short)f2bf(w.y); v[6]=(short)f2bf(w.z); v[7]=(short)f2bf(w.w);
    *(bf16x8*)(ET3 + ((size_t)dcb * K_ + k) * 64 + ((c ^ (k & 7)) * 8)) = v;
}

__global__ __launch_bounds__(256)
void cvt_z(const float* __restrict__ z, short* __restrict__ ZT3) {
    int tid = blockIdx.x * 256 + threadIdx.x;   // 0..65535
    int dcb = tid >> 14;
    int n   = tid & 16383;
    int b   = n >> 10;
    int s   = n & 1023;
    const float* zb = z + (size_t)b * ZB + (size_t)dcb * 64 * SP + s;
    short* dst = ZT3 + ((size_t)dcb * N_TOT + n) * 64;
    int sw = n & 7;
#pragma unroll
    for (int c = 0; c < 8; ++c) {
        bf16x8 v;
#pragma unroll
        for (int j = 0; j < 8; ++j)
            v[j] = (short)f2bf(zb[(size_t)(c * 8 + j) * SP]);
        *(bf16x8*)(dst + ((c ^ sw) * 8)) = v;
    }
}

// ======================= MFMA GEMM + packed-key top-2 =======================
// Block: 128 z-rows x 1024-code stripe; chunks of 128 codes; BK=64 staging.
// 4 waves 2x2 (wm: code half, wn: row half). Running top-2 u32 keys per
// (row, stripe, wm) group (G=512 codes). key = (bits(enorm+BIAS-2dot) & ~8191)|code.

__global__ __launch_bounds__(256, 4)
void mfma_argmin2(const short* __restrict__ ET3, const short* __restrict__ ZT3,
                  const float* __restrict__ enormB, uint2* __restrict__ pv) {
    __shared__ char smem[32768];                // As 16KB | Bs 16KB
    const int t    = threadIdx.x;
    const int wid  = t >> 6, lane = t & 63;
    const int quad = lane >> 4, l16 = lane & 15;
    const int wm   = wid >> 1, wn = wid & 1;
    const int stripe = blockIdx.x >> 7;         // stripe-major for L2 reuse
    const int n0     = (blockIdx.x & 127) * 128;
    const int swz    = (l16 & 7);

    unsigned r1[4], r2[4];
#pragma unroll
    for (int fj = 0; fj < 4; ++fj) { r1[fj] = 0xFFFFFFFFu; r2[fj] = 0xFFFFFFFFu; }

#pragma unroll 1
    for (int cc = 0; cc < 8; ++cc) {
        const int c0 = stripe * 1024 + cc * 128;
        f32x4 acc[4][4];
#pragma unroll
        for (int fi = 0; fi < 4; ++fi)
#pragma unroll
            for (int fj = 0; fj < 4; ++fj) acc[fi][fj] = (f32x4){0.f, 0.f, 0.f, 0.f};

#pragma unroll 1
        for (int dcb = 0; dcb < 4; ++dcb) {
            __syncthreads();
            const char* gA = (const char*)ET3 + ((size_t)dcb * K_    + c0) * 128;
            const char* gB = (const char*)ZT3 + ((size_t)dcb * N_TOT + n0) * 128;
#pragma unroll
            for (int j = 0; j < 4; ++j) {
                int off = j * 4096 + t * 16;
                GLOAD_LDS16(gA + off, smem + off);
                GLOAD_LDS16(gB + off, smem + 16384 + off);
            }
            __syncthreads();
#pragma unroll
            for (int dc2 = 0; dc2 < 2; ++dc2) {
                bf16x8 af[4], bfv[4];
                const int ch = ((dc2 * 4 + quad) ^ swz) * 16;
#pragma unroll
                for (int fi = 0; fi < 4; ++fi)
                    af[fi] = *(const bf16x8*)(smem + (wm*64 + fi*16 + l16)*128 + ch);
#pragma unroll
                for (int fj = 0; fj < 4; ++fj)
                    bfv[fj] = *(const bf16x8*)(smem + 16384 + (wn*64 + fj*16 + l16)*128 + ch);
#pragma unroll
                for (int fi = 0; fi < 4; ++fi)
#pragma unroll
                    for (int fj = 0; fj < 4; ++fj)
                        acc[fi][fj] = __builtin_amdgcn_mfma_f32_16x16x32_bf16(
                            af[fi], bfv[fj], acc[fi][fj], 0, 0, 0);
            }
        }

        // epilogue: branchless packed-key top-2 merge (u32 lex (quant-s, code))
        float ekv[4][4];
#pragma unroll
        for (int fi = 0; fi < 4; ++fi) {
            float4 e4 = *(const float4*)(enormB + c0 + wm*64 + fi*16 + quad*4);
            ekv[fi][0]=e4.x; ekv[fi][1]=e4.y; ekv[fi][2]=e4.z; ekv[fi][3]=e4.w;
        }
#pragma unroll
        for (int fj = 0; fj < 4; ++fj) {
#pragma unroll
            for (int fi = 0; fi < 4; ++fi) {
                const unsigned cb = (unsigned)(c0 + wm*64 + fi*16 + quad*4);
                unsigned k0, k1, k2, k3;
                {
                    float s0 = fmaf(-2.f, acc[fi][fj].x, ekv[fi][0]);
                    float s1 = fmaf(-2.f, acc[fi][fj].y, ekv[fi][1]);
                    float s2 = fmaf(-2.f, acc[fi][fj].z, ekv[fi][2]);
                    float s3 = fmaf(-2.f, acc[fi][fj].w, ekv[fi][3]);
                    k0 = (__float_as_uint(s0) & 0xFFFFE000u) | (cb + 0u);
                    k1 = (__float_as_uint(s1) & 0xFFFFE000u) | (cb + 1u);
                    k2 = (__float_as_uint(s2) & 0xFFFFE000u) | (cb + 2u);
                    k3 = (__float_as_uint(s3) & 0xFFFFE000u) | (cb + 3u);
                }
                unsigned lo1 = min(k0, k1), hi1 = max(k0, k1);
                unsigned lo2 = min(k2, k3), hi2 = max(k2, k3);
                merge2(lo1, hi1, lo2, hi2);
                merge2(r1[fj], r2[fj], lo1, hi1);
            }
        }
    }

    // cross-quad merge (^16, ^32) and store per (row, stripe, wm) group
#pragma unroll
    for (int fj = 0; fj < 4; ++fj) {
        unsigned a1 = r1[fj], a2 = r2[fj];
#pragma unroll
        for (int m = 16; m <= 32; m <<= 1) {
            unsigned b1 = __shfl_xor(a1, m, 64);
            unsigned b2 = __shfl_xor(a2, m, 64);
            merge2(a1, a2, b1, b2);
        }
        if (quad == 0) {
            int n = n0 + wn*64 + fj*16 + l16;
            pv[(size_t)(stripe * 2 + wm) * N_TOT + n] = make_uint2(a1, a2);
        }
    }
}

// ======================= window reduce + exact recheck =======================

__global__ __launch_bounds__(256)
void reduce_exact2(const uint2* __restrict__ pv, const float* __restrict__ znorm,
                   const float* __restrict__ enorm, const float* __restrict__ z,
                   const float* __restrict__ emb, int* __restrict__ fidx,
                   float* __restrict__ out_idx) {
    int n = blockIdx.x * 256 + threadIdx.x;
    unsigned mn = 0xFFFFFFFFu;
#pragma unroll
    for (int g = 0; g < 16; ++g) {
        uint2 p = pv[(size_t)g * N_TOT + n];
        mn = min(mn, p.x);                       // p.x <= p.y
    }
    float smin  = __uint_as_float(mn & 0xFFFFE000u);
    unsigned th = __float_as_uint(smin + DELTA_) | 8191u;
    int cnt = 0;
#pragma unroll
    for (int g = 0; g < 16; ++g) {
        uint2 p = pv[(size_t)g * N_TOT + n];
        cnt += (p.x <= th) ? 1 : 0;
        cnt += (p.y <= th) ? 1 : 0;
    }
    int bc = (int)(mn & 8191u);
    if (cnt > 1) {
        // exact reference arithmetic: s = fl(fl(zn+ek) - fl(2*dot)), dot
        // sequential fp32 fmaf d=0..255 (verified absmax=0 in rounds 1-2).
        int b = n >> 10, sp = n & 1023;
        const float* zr = z + (size_t)b * ZB + sp;
        float zn = znorm[n];
        float bs = 3.4e38f; int bcc = 0x7fffffff;
        for (int g = 0; g < 16; ++g) {
            uint2 p = pv[(size_t)g * N_TOT + n];
#pragma unroll
            for (int h = 0; h < 2; ++h) {
                unsigned key = h ? p.y : p.x;
                if (key <= th) {
                    int c = (int)(key & 8191u);
                    const float* er = emb + (size_t)c * D_;
                    float dot = 0.f;
                    for (int d = 0; d < D_; ++d)
                        dot = fmaf(zr[(size_t)d * SP], er[d], dot);
                    float s = (zn + enorm[c]) - 2.f * dot;
                    if (s < bs || (s == bs && c < bcc)) { bs = s; bcc = c; }
                }
            }
        }
        bc = bcc;
    }
    fidx[n] = bc;
    out_idx[n] = (float)bc;
}

// ======================= output / loss (LDS-staged gather) =======================

__global__ __launch_bounds__(256)
void output_kernel2(const float* __restrict__ z, const float* __restrict__ emb,
                    const int* __restrict__ fidx, float* __restrict__ out,
                    float* __restrict__ loss) {
    __shared__ float eL[32][257];
    __shared__ int   fid[32];
    __shared__ float red[4];
    const int nb = blockIdx.x;      // 0..511
    const int n0 = nb * 32;
    const int b  = n0 >> 10;
    const int s0 = n0 & 1023;
    const int t  = threadIdx.x;
    if (t < 32) fid[t] = fidx[n0 + t];
    __syncthreads();
#pragma unroll
    for (int i = 0; i < 8; ++i) {
        int p = t + i * 256;        // 2048 float4 slots: row=p>>6, q=p&63
        int row = p >> 6, q = p & 63;
        float4 v = *(const float4*)(emb + (size_t)fid[row] * D_ + q * 4);
        eL[row][q*4+0] = v.x; eL[row][q*4+1] = v.y;
        eL[row][q*4+2] = v.z; eL[row][q*4+3] = v.w;
    }
    __syncthreads();
    const int sl = t & 31, dg = t >> 5;
    float lsum = 0.f;
#pragma unroll
    for (int i = 0; i < 32; ++i) {
        int d = dg * 32 + i;
        size_t off = ((size_t)(b * D_ + d)) * SP + s0 + sl;
        float zv = z[off];
        float q  = eL[sl][d];
        float diff = q - zv;                 // fl(q - z)
        out[off] = zv + diff;                // straight-through fl(z + fl(q-z))
        lsum += diff * diff;
    }
    for (int m = 1; m < 64; m <<= 1) lsum += __shfl_xor(lsum, m, 64);
    if ((t & 63) == 0) red[t >> 6] = lsum;
    __syncthreads();
    if (t == 0) {
        float tot = (red[0] + red[1] + red[2] + red[3])
                    * (1.25f / (float)(B_ * SP * D_));
        atomicAdd(loss, tot);
    }
}

// ======================= fallback path (round-1 fp32, proven) =======================
#define MT 128
#define CT 128
#define DT 32
#define NSTRIPE 8
#define CPS (K_/NSTRIPE)
#define ES (CT+4)

__global__ __launch_bounds__(256)
void gemm_argmin(const float* __restrict__ z, const float* __restrict__ emb,
                 const float* __restrict__ enorm, const float* __restrict__ znorm,
                 float* __restrict__ pvals, int* __restrict__ pidx) {
    __shared__ float zsm[DT][MT];
    __shared__ float esm[DT][ES];
    const int t = threadIdx.x;
    const int bx = blockIdx.x;
    const int stripe = bx & (NSTRIPE - 1);
    const int rb = bx >> 3;
    const int n0 = rb * MT;
    const int b  = n0 / SP;
    const int s0 = n0 % SP;
    const float* zb = z + (size_t)b * ZB + s0;
    const int tc = t & 15;
    const int tr = t >> 4;
    float zn[8];
#pragma unroll
    for (int i = 0; i < 8; ++i) zn[i] = znorm[n0 + tr * 8 + i];
    float best[8]; int bidx[8];
#pragma unroll
    for (int i = 0; i < 8; ++i) { best[i] = 3.4e38f; bidx[i] = 0; }
    for (int cc = 0; cc < CPS / CT; ++cc) {
        const int c0 = stripe * CPS + cc * CT;
        float acc[8][8];
#pragma unroll
        for (int i = 0; i < 8; ++i)
#pragma unroll
            for (int j = 0; j < 8; ++j) acc[i][j] = 0.f;
        for (int dc = 0; dc < D_ / DT; ++dc) {
            const int d0 = dc * DT;
            __syncthreads();
#pragma unroll
            for (int i = 0; i < 4; ++i) {
                int p  = t + i * 256;
                int d  = p >> 5;
                int rq = p & 31;
                float4 v = *(const float4*)(zb + (size_t)(d0 + d) * SP + rq * 4);
                *(float4*)&zsm[d][rq * 4] = v;
            }
#pragma unroll
            for (int i = 0; i < 4; ++i) {
                int p  = t + i * 256;
                int c  = p >> 3;
                int dq = p & 7;
                float4 v = *(const float4*)(emb + (size_t)(c0 + c) * D_ + d0 + dq * 4);
                esm[dq * 4 + 0][c] = v.x;
                esm[dq * 4 + 1][c] = v.y;
                esm[dq * 4 + 2][c] = v.z;
                esm[dq * 4 + 3][c] = v.w;
            }
            __syncthreads();
#pragma unroll 8
            for (int d = 0; d < DT; ++d) {
                float zr[8], ec[8];
                *(float4*)&zr[0] = *(const float4*)&zsm[d][tr * 8];
                *(float4*)&zr[4] = *(const float4*)&zsm[d][tr * 8 + 4];
                *(float4*)&ec[0] = *(const float4*)&esm[d][tc * 8];
                *(float4*)&ec[4] = *(const float4*)&esm[d][tc * 8 + 4];
#pragma unroll
                for (int i = 0; i < 8; ++i)
#pragma unroll
                    for (int j = 0; j < 8; ++j)
                        acc[i][j] = fmaf(zr[i], ec[j], acc[i][j]);
            }
        }
        float ek[8];
#pragma unroll
        for (int j = 0; j < 8; ++j) ek[j] = enorm[c0 + tc * 8 + j];
#pragma unroll
        for (int i = 0; i < 8; ++i) {
#pragma unroll
            for (int j = 0; j < 8; ++j) {
                float s = (zn[i] + ek[j]) - 2.0f * acc[i][j];
                int code = c0 + tc * 8 + j;
                if (s < best[i] || (s == best[i] && code < bidx[i])) {
                    best[i] = s; bidx[i] = code;
                }
            }
        }
    }
#pragma unroll
    for (int i = 0; i < 8; ++i) {
        float v = best[i]; int ix = bidx[i];
        for (int m = 1; m < 16; m <<= 1) {
            float ov = __shfl_xor(v, m, 64);
            int   oi = __shfl_xor(ix, m, 64);
            if (ov < v || (ov == v && oi < ix)) { v = ov; ix = oi; }
        }
        if (tc == 0) {
            int n = n0 + tr * 8 + i;
            pvals[n * NSTRIPE + stripe] = v;
            pidx [n * NSTRIPE + stripe] = ix;
        }
    }
}

__global__ __launch_bounds__(256)
void reduce_rows(const float* __restrict__ pvals, const int* __restrict__ pidx,
                 int* __restrict__ fidx, float* __restrict__ out_idx) {
    int n = blockIdx.x * 256 + threadIdx.x;
    float bv = 3.4e38f; int bi = 0;
#pragma unroll
    for (int s = 0; s < NSTRIPE; ++s) {
        float v = pvals[n * NSTRIPE + s];
        int  ix = pidx [n * NSTRIPE + s];
        if (v < bv || (v == bv && ix < bi)) { bv = v; bi = ix; }
    }
    fidx[n] = bi;
    out_idx[n] = (float)bi;
}

// ======================= launch =======================
// fast ws layout (floats):
//   enorm [0,8192) enormB [8192,16384) znorm [16384,32768) fidx [32768,49152)
//   pv    [49152,573440)   (16 groups x 16384 uint2; zpart aliases its head)
//   ET3   [573440,1622016) (bf16)    ZT3 [1622016,3719168) (bf16)
// NEED = 3,719,168*4 = 14,876,672 B (< proven 15.9 MB grant)

extern "C" void kernel_launch(void* const* d_in, const int* in_sizes, int n_in,
                              void* d_out, int out_size, void* d_ws, size_t ws_size,
                              hipStream_t stream) {
    const float* z   = (const float*)d_in[0];
    const float* emb = (const float*)d_in[1];
    float* out = (float*)d_out;
    float* w   = (float*)d_ws;

    float* enorm  = w;
    float* enormB = w + 8192;
    float* znorm  = w + 16384;
    int*   fidx   = (int*)(w + 32768);

    float* out0     = out;
    float* out_loss = out + (size_t)B_ * D_ * SP;
    float* out_idx  = out_loss + 1;

    const size_t NEED = 3719168ULL * 4ULL;
    if (ws_size >= NEED) {
        uint2* pv    = (uint2*)(w + 49152);
        float* zpart = w + 49152;              // aliases pv (dead before pv written)
        short* ET3   = (short*)(w + 573440);
        short* ZT3   = (short*)(w + 1622016);

        enorm_kernel<<<K_ / 4, 256, 0, stream>>>(emb, enorm, enormB);
        zpart_kernel<<<B_ * 16, 256, 0, stream>>>(z, zpart);
        znorm_kernel<<<N_TOT / 256, 256, 0, stream>>>(zpart, znorm);
        cvt_e<<<1024, 256, 0, stream>>>(emb, ET3);
        cvt_z<<<256, 256, 0, stream>>>(z, ZT3);
        mfma_argmin2<<<1024, 256, 0, stream>>>(ET3, ZT3, enormB, pv);
        reduce_exact2<<<N_TOT / 256, 256, 0, stream>>>(pv, znorm, enorm, z, emb,
                                                       fidx, out_idx);
    } else {
        // round-1 fp32 fallback layout
        float* zpart = w + 8192 + 262144 - 262144 + 8192;  // [16384..) keep distinct
        zpart        = w + 16384 + 16384;                  // [32768, 294912)
        float* znF   = w + 294912;                         // [294912, 311296)
        float* pvals = w + 311296;                         // [311296, 442368)
        int*   pidxF = (int*)(w + 442368);                 // [442368, 573440)
        int*   fidxF = (int*)(w + 573440);
        fidx = fidxF;
        enorm_kernel<<<K_ / 4, 256, 0, stream>>>(emb, enorm, enormB);
        zpart_kernel<<<B_ * 16, 256, 0, stream>>>(z, zpart);
        znorm_kernel<<<N_TOT / 256, 256, 0, stream>>>(zpart, znF);
        gemm_argmin<<<(N_TOT / MT) * NSTRIPE, 256, 0, stream>>>(z, emb, enorm, znF,
                                                                pvals, pidxF);
        reduce_rows<<<N_TOT / 256, 256, 0, stream>>>(pvals, pidxF, fidxF, out_idx);
    }

    hipMemsetAsync(out_loss, 0, sizeof(float), stream);
    output_kernel2<<<N_TOT / 32, 256, 0, stream>>>(z, emb, fidx, out0, out_loss);
}

// Round 4
// 259.741 us; speedup vs baseline: 3.7413x; 1.4123x over previous
//
#include <hip/hip_runtime.h>

#define B_    16
#define D_    256
#define H_    32
#define W_    32
#define SP    1024        // H_*W_
#define N_TOT 16384       // B_*SP
#define K_    8192
#define ZB    (D_*SP)     // floats per batch in z

#define BIAS_  0.03125f
#define DELTA_ 2.5e-4f

typedef __attribute__((ext_vector_type(8))) short bf16x8;
typedef __attribute__((ext_vector_type(4))) float f32x4;

#define GLOAD_LDS16(g, l) \
    __builtin_amdgcn_global_load_lds((const __attribute__((address_space(1))) void*)(g), \
                                     (__attribute__((address_space(3))) void*)(l), 16, 0, 0)

__device__ __forceinline__ unsigned short f2bf(float f) {
    unsigned u = __float_as_uint(f);
    u += 0x7FFFu + ((u >> 16) & 1u);          // RNE
    return (unsigned short)(u >> 16);
}

// merge two sorted pairs (a1<=a2), (b1<=b2) -> top-2 in (a1,a2). u32 lex keys.
__device__ __forceinline__ void merge2(unsigned &a1, unsigned &a2,
                                       unsigned b1, unsigned b2) {
    unsigned m1  = min(a1, b1);
    unsigned hi  = max(a1, b1);
    unsigned sel = (a1 < b1) ? a2 : b2;
    a2 = min(hi, sel);
    a1 = m1;
}

// ======================= pre-passes =======================

__global__ __launch_bounds__(256)
void enorm_kernel(const float* __restrict__ emb, float* __restrict__ enorm,
                  float* __restrict__ enormB) {
    int t = threadIdx.x;
    int k = blockIdx.x * 4 + (t >> 6);
    int l = t & 63;
    float4 v = *(const float4*)(emb + (size_t)k * D_ + l * 4);
    float sum = v.x*v.x + v.y*v.y + v.z*v.z + v.w*v.w;
    for (int m = 1; m < 64; m <<= 1) sum += __shfl_xor(sum, m, 64);
    if (l == 0) { enorm[k] = sum; enormB[k] = sum + BIAS_; }
}

__global__ __launch_bounds__(256)
void zpart_kernel(const float* __restrict__ z, float* __restrict__ zpart) {
    int bx = blockIdx.x;          // b*16 + dc
    int b  = bx >> 4;
    int dc = bx & 15;
    int t  = threadIdx.x;
#pragma unroll
    for (int i = 0; i < 4; ++i) {
        int s = t + i * 256;
        float sum = 0.f;
#pragma unroll
        for (int dd = 0; dd < 16; ++dd) {
            float v = z[(size_t)b * ZB + (size_t)(dc * 16 + dd) * SP + s];
            sum += v * v;
        }
        zpart[(size_t)dc * N_TOT + b * SP + s] = sum;
    }
}

__global__ __launch_bounds__(256)
void znorm_kernel(const float* __restrict__ zpart, float* __restrict__ znorm) {
    int n = blockIdx.x * 256 + threadIdx.x;
    float sum = 0.f;
#pragma unroll
    for (int dc = 0; dc < 16; ++dc) sum += zpart[(size_t)dc * N_TOT + n];
    znorm[n] = sum;
}

// ======================= bf16 conversion (swizzled layouts) =======================

__global__ __launch_bounds__(256)
void cvt_e(const float* __restrict__ emb, short* __restrict__ ET3) {
    int tid = blockIdx.x * 256 + threadIdx.x;   // 0..262143
    int k   = tid >> 5;
    int dcb = (tid >> 3) & 3;
    int c   = tid & 7;
    const float* src = emb + (size_t)k * D_ + dcb * 64 + c * 8;
    float4 u = *(const float4*)src;
    float4 w = *(const float4*)(src + 4);
    bf16x8 v;
    v[0]=(short)f2bf(u.x); v[1]=(short)f2bf(u.y); v[2]=(short)f2bf(u.z); v[3]=(short)f2bf(u.w);
    v[4]=(short)f2bf(w.x); v[5]=(short)f2bf(w.y); v[6]=(short)f2bf(w.z); v[7]=(short)f2bf(w.w);
    *(bf16x8*)(ET3 + ((size_t)dcb * K_ + k) * 64 + ((c ^ (k & 7)) * 8)) = v;
}

__global__ __launch_bounds__(256)
void cvt_z(const float* __restrict__ z, short* __restrict__ ZT3) {
    int tid = blockIdx.x * 256 + threadIdx.x;   // 0..65535
    int dcb = tid >> 14;
    int n   = tid & 16383;
    int b   = n >> 10;
    int s   = n & 1023;
    const float* zb = z + (size_t)b * ZB + (size_t)dcb * 64 * SP + s;
    short* dst = ZT3 + ((size_t)dcb * N_TOT + n) * 64;
    int sw = n & 7;
#pragma unroll
    for (int c = 0; c < 8; ++c) {
        bf16x8 v;
#pragma unroll
        for (int j = 0; j < 8; ++j)
            v[j] = (short)f2bf(zb[(size_t)(c * 8 + j) * SP]);
        *(bf16x8*)(dst + ((c ^ sw) * 8)) = v;
    }
}

// ======================= MFMA GEMM + packed-key top-2 =======================

__global__ __launch_bounds__(256, 4)
void mfma_argmin2(const short* __restrict__ ET3, const short* __restrict__ ZT3,
                  const float* __restrict__ enormB, uint2* __restrict__ pv) {
    __shared__ char smem[32768];                // As 16KB | Bs 16KB
    const int t    = threadIdx.x;
    const int wid  = t >> 6, lane = t & 63;
    const int quad = lane >> 4, l16 = lane & 15;
    const int wm   = wid >> 1, wn = wid & 1;
    const int stripe = blockIdx.x >> 7;
    const int n0     = (blockIdx.x & 127) * 128;
    const int swz    = (l16 & 7);

    unsigned r1[4], r2[4];
#pragma unroll
    for (int fj = 0; fj < 4; ++fj) { r1[fj] = 0xFFFFFFFFu; r2[fj] = 0xFFFFFFFFu; }

#pragma unroll 1
    for (int cc = 0; cc < 8; ++cc) {
        const int c0 = stripe * 1024 + cc * 128;
        f32x4 acc[4][4];
#pragma unroll
        for (int fi = 0; fi < 4; ++fi)
#pragma unroll
            for (int fj = 0; fj < 4; ++fj) acc[fi][fj] = (f32x4){0.f, 0.f, 0.f, 0.f};

#pragma unroll 1
        for (int dcb = 0; dcb < 4; ++dcb) {
            __syncthreads();
            const char* gA = (const char*)ET3 + ((size_t)dcb * K_    + c0) * 128;
            const char* gB = (const char*)ZT3 + ((size_t)dcb * N_TOT + n0) * 128;
#pragma unroll
            for (int j = 0; j < 4; ++j) {
                int off = j * 4096 + t * 16;
                GLOAD_LDS16(gA + off, smem + off);
                GLOAD_LDS16(gB + off, smem + 16384 + off);
            }
            __syncthreads();
#pragma unroll
            for (int dc2 = 0; dc2 < 2; ++dc2) {
                bf16x8 af[4], bfv[4];
                const int ch = ((dc2 * 4 + quad) ^ swz) * 16;
#pragma unroll
                for (int fi = 0; fi < 4; ++fi)
                    af[fi] = *(const bf16x8*)(smem + (wm*64 + fi*16 + l16)*128 + ch);
#pragma unroll
                for (int fj = 0; fj < 4; ++fj)
                    bfv[fj] = *(const bf16x8*)(smem + 16384 + (wn*64 + fj*16 + l16)*128 + ch);
#pragma unroll
                for (int fi = 0; fi < 4; ++fi)
#pragma unroll
                    for (int fj = 0; fj < 4; ++fj)
                        acc[fi][fj] = __builtin_amdgcn_mfma_f32_16x16x32_bf16(
                            af[fi], bfv[fj], acc[fi][fj], 0, 0, 0);
            }
        }

        float ekv[4][4];
#pragma unroll
        for (int fi = 0; fi < 4; ++fi) {
            float4 e4 = *(const float4*)(enormB + c0 + wm*64 + fi*16 + quad*4);
            ekv[fi][0]=e4.x; ekv[fi][1]=e4.y; ekv[fi][2]=e4.z; ekv[fi][3]=e4.w;
        }
#pragma unroll
        for (int fj = 0; fj < 4; ++fj) {
#pragma unroll
            for (int fi = 0; fi < 4; ++fi) {
                const unsigned cb = (unsigned)(c0 + wm*64 + fi*16 + quad*4);
                unsigned k0, k1, k2, k3;
                {
                    float s0 = fmaf(-2.f, acc[fi][fj].x, ekv[fi][0]);
                    float s1 = fmaf(-2.f, acc[fi][fj].y, ekv[fi][1]);
                    float s2 = fmaf(-2.f, acc[fi][fj].z, ekv[fi][2]);
                    float s3 = fmaf(-2.f, acc[fi][fj].w, ekv[fi][3]);
                    k0 = (__float_as_uint(s0) & 0xFFFFE000u) | (cb + 0u);
                    k1 = (__float_as_uint(s1) & 0xFFFFE000u) | (cb + 1u);
                    k2 = (__float_as_uint(s2) & 0xFFFFE000u) | (cb + 2u);
                    k3 = (__float_as_uint(s3) & 0xFFFFE000u) | (cb + 3u);
                }
                unsigned lo1 = min(k0, k1), hi1 = max(k0, k1);
                unsigned lo2 = min(k2, k3), hi2 = max(k2, k3);
                merge2(lo1, hi1, lo2, hi2);
                merge2(r1[fj], r2[fj], lo1, hi1);
            }
        }
    }

#pragma unroll
    for (int fj = 0; fj < 4; ++fj) {
        unsigned a1 = r1[fj], a2 = r2[fj];
#pragma unroll
        for (int m = 16; m <= 32; m <<= 1) {
            unsigned b1 = __shfl_xor(a1, m, 64);
            unsigned b2 = __shfl_xor(a2, m, 64);
            merge2(a1, a2, b1, b2);
        }
        if (quad == 0) {
            int n = n0 + wn*64 + fj*16 + l16;
            pv[(size_t)(stripe * 2 + wm) * N_TOT + n] = make_uint2(a1, a2);
        }
    }
}

// ======================= phase A: window classify + compact =======================

__global__ __launch_bounds__(256)
void reduce_phaseA(const uint2* __restrict__ pv, int* __restrict__ fidx,
                   float* __restrict__ out_idx, int* __restrict__ wl,
                   int* __restrict__ wl_cnt) {
    int n = blockIdx.x * 256 + threadIdx.x;
    uint2 pp[16];
    unsigned mn = 0xFFFFFFFFu;
#pragma unroll
    for (int g = 0; g < 16; ++g) {
        pp[g] = pv[(size_t)g * N_TOT + n];
        mn = min(mn, pp[g].x);
    }
    float smin  = __uint_as_float(mn & 0xFFFFE000u);
    unsigned th = __float_as_uint(smin + DELTA_) | 8191u;
    int cnt = 0;
#pragma unroll
    for (int g = 0; g < 16; ++g) {
        cnt += (pp[g].x <= th) ? 1 : 0;
        cnt += (pp[g].y <= th) ? 1 : 0;
    }
    if (cnt > 1) {
        int slot = atomicAdd(wl_cnt, 1);
        wl[slot] = n;
    } else {
        int c = (int)(mn & 8191u);
        fidx[n] = c;
        out_idx[n] = (float)c;
    }
}

// ======================= phase B: one wave per recheck row =======================
// Exact reference arithmetic per candidate: sequential fmaf d=0..255,
// s = (zn + ek) - 2*dot (bit-identical to rounds 1-3's verified recheck).
// Lane c handles candidate c; z row staged in per-wave LDS (parallel gather).

__global__ __launch_bounds__(256)
void recheck_kernel(const uint2* __restrict__ pv, const float* __restrict__ znorm,
                    const float* __restrict__ enorm, const float* __restrict__ z,
                    const float* __restrict__ emb, const int* __restrict__ wl,
                    const int* __restrict__ wl_cnt, int* __restrict__ fidx,
                    float* __restrict__ out_idx) {
    __shared__ float zrow[4][256];
    const int lane = threadIdx.x & 63;
    const int wslot = threadIdx.x >> 6;
    const int gwave = (blockIdx.x * 256 + threadIdx.x) >> 6;
    const int nwaves = (gridDim.x * 256) >> 6;
    const int total = *wl_cnt;

    for (int i = gwave; i < total; i += nwaves) {
        int n = wl[i];
        unsigned key = 0xFFFFFFFFu;
        if (lane < 32) {
            uint2 p = pv[(size_t)(lane & 15) * N_TOT + n];
            key = (lane < 16) ? p.x : p.y;
        }
        unsigned mn = key;
#pragma unroll
        for (int m = 1; m < 64; m <<= 1) mn = min(mn, __shfl_xor(mn, m, 64));
        float smin  = __uint_as_float(mn & 0xFFFFE000u);
        unsigned th = __float_as_uint(smin + DELTA_) | 8191u;

        const int b = n >> 10, sp = n & 1023;
        const float* zr = z + (size_t)b * ZB + sp;
        // cooperative strided gather of the z row (wave-synchronous LDS slot)
#pragma unroll
        for (int j = 0; j < 4; ++j)
            zrow[wslot][lane + j * 64] = zr[(size_t)(lane + j * 64) * SP];
        float zn = znorm[n];

        unsigned lexlo = 0xFFFFFFFFu, lexhi = 0xFFFFFFFFu;
        if (key <= th) {
            int c = (int)(key & 8191u);
            const float* er = emb + (size_t)c * D_;
            float dot = 0.f;
#pragma unroll 8
            for (int d = 0; d < D_; ++d)
                dot = fmaf(zrow[wslot][d], er[d], dot);
            float s = (zn + enorm[c]) - 2.f * dot;
            unsigned sb = __float_as_uint(s);
            lexhi = sb >> 19;
            lexlo = (sb << 13) | (unsigned)c;
        }
#pragma unroll
        for (int m = 1; m < 64; m <<= 1) {
            unsigned olo = __shfl_xor(lexlo, m, 64);
            unsigned ohi = __shfl_xor(lexhi, m, 64);
            if (ohi < lexhi || (ohi == lexhi && olo < lexlo)) { lexhi = ohi; lexlo = olo; }
        }
        if (lane == 0) {
            int c = (int)(lexlo & 8191u);
            fidx[n] = c;
            out_idx[n] = (float)c;
        }
    }
}

// ======================= output / loss (LDS-staged gather) =======================

__global__ __launch_bounds__(256)
void output_kernel2(const float* __restrict__ z, const float* __restrict__ emb,
                    const int* __restrict__ fidx, float* __restrict__ out,
                    float* __restrict__ loss) {
    __shared__ float eL[32][257];
    __shared__ int   fid[32];
    __shared__ float red[4];
    const int nb = blockIdx.x;      // 0..511
    const int n0 = nb * 32;
    const int b  = n0 >> 10;
    const int s0 = n0 & 1023;
    const int t  = threadIdx.x;
    if (t < 32) fid[t] = fidx[n0 + t];
    __syncthreads();
#pragma unroll
    for (int i = 0; i < 8; ++i) {
        int p = t + i * 256;
        int row = p >> 6, q = p & 63;
        float4 v = *(const float4*)(emb + (size_t)fid[row] * D_ + q * 4);
        eL[row][q*4+0] = v.x; eL[row][q*4+1] = v.y;
        eL[row][q*4+2] = v.z; eL[row][q*4+3] = v.w;
    }
    __syncthreads();
    const int sl = t & 31, dg = t >> 5;
    float lsum = 0.f;
#pragma unroll
    for (int i = 0; i < 32; ++i) {
        int d = dg * 32 + i;
        size_t off = ((size_t)(b * D_ + d)) * SP + s0 + sl;
        float zv = z[off];
        float q  = eL[sl][d];
        float diff = q - zv;
        out[off] = zv + diff;
        lsum += diff * diff;
    }
    for (int m = 1; m < 64; m <<= 1) lsum += __shfl_xor(lsum, m, 64);
    if ((t & 63) == 0) red[t >> 6] = lsum;
    __syncthreads();
    if (t == 0) {
        float tot = (red[0] + red[1] + red[2] + red[3])
                    * (1.25f / (float)(B_ * SP * D_));
        atomicAdd(loss, tot);
    }
}

// ======================= fallback path (round-1 fp32, proven) =======================
#define MT 128
#define CT 128
#define DT 32
#define NSTRIPE 8
#define CPS (K_/NSTRIPE)
#define ES (CT+4)

__global__ __launch_bounds__(256)
void gemm_argmin(const float* __restrict__ z, const float* __restrict__ emb,
                 const float* __restrict__ enorm, const float* __restrict__ znorm,
                 float* __restrict__ pvals, int* __restrict__ pidx) {
    __shared__ float zsm[DT][MT];
    __shared__ float esm[DT][ES];
    const int t = threadIdx.x;
    const int bx = blockIdx.x;
    const int stripe = bx & (NSTRIPE - 1);
    const int rb = bx >> 3;
    const int n0 = rb * MT;
    const int b  = n0 / SP;
    const int s0 = n0 % SP;
    const float* zb = z + (size_t)b * ZB + s0;
    const int tc = t & 15;
    const int tr = t >> 4;
    float zn[8];
#pragma unroll
    for (int i = 0; i < 8; ++i) zn[i] = znorm[n0 + tr * 8 + i];
    float best[8]; int bidx[8];
#pragma unroll
    for (int i = 0; i < 8; ++i) { best[i] = 3.4e38f; bidx[i] = 0; }
    for (int cc = 0; cc < CPS / CT; ++cc) {
        const int c0 = stripe * CPS + cc * CT;
        float acc[8][8];
#pragma unroll
        for (int i = 0; i < 8; ++i)
#pragma unroll
            for (int j = 0; j < 8; ++j) acc[i][j] = 0.f;
        for (int dc = 0; dc < D_ / DT; ++dc) {
            const int d0 = dc * DT;
            __syncthreads();
#pragma unroll
            for (int i = 0; i < 4; ++i) {
                int p  = t + i * 256;
                int d  = p >> 5;
                int rq = p & 31;
                float4 v = *(const float4*)(zb + (size_t)(d0 + d) * SP + rq * 4);
                *(float4*)&zsm[d][rq * 4] = v;
            }
#pragma unroll
            for (int i = 0; i < 4; ++i) {
                int p  = t + i * 256;
                int c  = p >> 3;
                int dq = p & 7;
                float4 v = *(const float4*)(emb + (size_t)(c0 + c) * D_ + d0 + dq * 4);
                esm[dq * 4 + 0][c] = v.x;
                esm[dq * 4 + 1][c] = v.y;
                esm[dq * 4 + 2][c] = v.z;
                esm[dq * 4 + 3][c] = v.w;
            }
            __syncthreads();
#pragma unroll 8
            for (int d = 0; d < DT; ++d) {
                float zr[8], ec[8];
                *(float4*)&zr[0] = *(const float4*)&zsm[d][tr * 8];
                *(float4*)&zr[4] = *(const float4*)&zsm[d][tr * 8 + 4];
                *(float4*)&ec[0] = *(const float4*)&esm[d][tc * 8];
                *(float4*)&ec[4] = *(const float4*)&esm[d][tc * 8 + 4];
#pragma unroll
                for (int i = 0; i < 8; ++i)
#pragma unroll
                    for (int j = 0; j < 8; ++j)
                        acc[i][j] = fmaf(zr[i], ec[j], acc[i][j]);
            }
        }
        float ek[8];
#pragma unroll
        for (int j = 0; j < 8; ++j) ek[j] = enorm[c0 + tc * 8 + j];
#pragma unroll
        for (int i = 0; i < 8; ++i) {
#pragma unroll
            for (int j = 0; j < 8; ++j) {
                float s = (zn[i] + ek[j]) - 2.0f * acc[i][j];
                int code = c0 + tc * 8 + j;
                if (s < best[i] || (s == best[i] && code < bidx[i])) {
                    best[i] = s; bidx[i] = code;
                }
            }
        }
    }
#pragma unroll
    for (int i = 0; i < 8; ++i) {
        float v = best[i]; int ix = bidx[i];
        for (int m = 1; m < 16; m <<= 1) {
            float ov = __shfl_xor(v, m, 64);
            int   oi = __shfl_xor(ix, m, 64);
            if (ov < v || (ov == v && oi < ix)) { v = ov; ix = oi; }
        }
        if (tc == 0) {
            int n = n0 + tr * 8 + i;
            pvals[n * NSTRIPE + stripe] = v;
            pidx [n * NSTRIPE + stripe] = ix;
        }
    }
}

__global__ __launch_bounds__(256)
void reduce_rows(const float* __restrict__ pvals, const int* __restrict__ pidx,
                 int* __restrict__ fidx, float* __restrict__ out_idx) {
    int n = blockIdx.x * 256 + threadIdx.x;
    float bv = 3.4e38f; int bi = 0;
#pragma unroll
    for (int s = 0; s < NSTRIPE; ++s) {
        float v = pvals[n * NSTRIPE + s];
        int  ix = pidx [n * NSTRIPE + s];
        if (v < bv || (v == bv && ix < bi)) { bv = v; bi = ix; }
    }
    fidx[n] = bi;
    out_idx[n] = (float)bi;
}

// ======================= launch =======================
// fast ws layout (floats):
//   enorm [0,8192) enormB [8192,16384) znorm [16384,32768) fidx [32768,49152)
//   wl_cnt [49152] (pad to 49216)   wl [49216,65600)  (pad to 65664)
//   pv    [65664,589952)  (16 groups x 16384 uint2; zpart aliases its head)
//   ET3   [589952,1638528) (bf16)   ZT3 [1638528,3735680) (bf16)
// NEED = 3,735,680*4 = 14,942,720 B (< proven 15.9 MB grant)

extern "C" void kernel_launch(void* const* d_in, const int* in_sizes, int n_in,
                              void* d_out, int out_size, void* d_ws, size_t ws_size,
                              hipStream_t stream) {
    const float* z   = (const float*)d_in[0];
    const float* emb = (const float*)d_in[1];
    float* out = (float*)d_out;
    float* w   = (float*)d_ws;

    float* enorm  = w;
    float* enormB = w + 8192;
    float* znorm  = w + 16384;
    int*   fidx   = (int*)(w + 32768);

    float* out0     = out;
    float* out_loss = out + (size_t)B_ * D_ * SP;
    float* out_idx  = out_loss + 1;

    const size_t NEED = 3735680ULL * 4ULL;
    if (ws_size >= NEED) {
        int*   wl_cnt = (int*)(w + 49152);
        int*   wl     = (int*)(w + 49216);
        uint2* pv     = (uint2*)(w + 65664);
        float* zpart  = w + 65664;             // aliases pv (dead before pv written)
        short* ET3    = (short*)(w + 589952);
        short* ZT3    = (short*)(w + 1638528);

        hipMemsetAsync(wl_cnt, 0, sizeof(int), stream);
        enorm_kernel<<<K_ / 4, 256, 0, stream>>>(emb, enorm, enormB);
        zpart_kernel<<<B_ * 16, 256, 0, stream>>>(z, zpart);
        znorm_kernel<<<N_TOT / 256, 256, 0, stream>>>(zpart, znorm);
        cvt_e<<<1024, 256, 0, stream>>>(emb, ET3);
        cvt_z<<<256, 256, 0, stream>>>(z, ZT3);
        mfma_argmin2<<<1024, 256, 0, stream>>>(ET3, ZT3, enormB, pv);
        reduce_phaseA<<<N_TOT / 256, 256, 0, stream>>>(pv, fidx, out_idx, wl, wl_cnt);
        recheck_kernel<<<256, 256, 0, stream>>>(pv, znorm, enorm, z, emb,
                                                wl, wl_cnt, fidx, out_idx);
    } else {
        float* zpart = w + 32768;              // [32768, 294912)
        float* znF   = w + 294912;             // [294912, 311296)
        float* pvals = w + 311296;             // [311296, 442368)
        int*   pidxF = (int*)(w + 442368);     // [442368, 573440)
        int*   fidxF = (int*)(w + 573440);
        fidx = fidxF;
        enorm_kernel<<<K_ / 4, 256, 0, stream>>>(emb, enorm, enormB);
        zpart_kernel<<<B_ * 16, 256, 0, stream>>>(z, zpart);
        znorm_kernel<<<N_TOT / 256, 256, 0, stream>>>(zpart, znF);
        gemm_argmin<<<(N_TOT / MT) * NSTRIPE, 256, 0, stream>>>(z, emb, enorm, znF,
                                                                pvals, pidxF);
        reduce_rows<<<N_TOT / 256, 256, 0, stream>>>(pvals, pidxF, fidx, out_idx);
    }

    hipMemsetAsync(out_loss, 0, sizeof(float), stream);
    output_kernel2<<<N_TOT / 32, 256, 0, stream>>>(z, emb, fidx, out0, out_loss);
}

// Round 5
// 230.726 us; speedup vs baseline: 4.2118x; 1.1258x over previous
//
#include <hip/hip_runtime.h>

#define B_    16
#define D_    256
#define H_    32
#define W_    32
#define SP    1024        // H_*W_
#define N_TOT 16384       // B_*SP
#define K_    8192
#define ZB    (D_*SP)     // floats per batch in z

#define BIAS_  0.03125f
#define DELTA_ 2.5e-4f

typedef __attribute__((ext_vector_type(8))) short bf16x8;
typedef __attribute__((ext_vector_type(4))) short bf16x4;
typedef __attribute__((ext_vector_type(4))) float f32x4;

#define GLOAD_LDS16(g, l) \
    __builtin_amdgcn_global_load_lds((const __attribute__((address_space(1))) void*)(g), \
                                     (__attribute__((address_space(3))) void*)(l), 16, 0, 0)

__device__ __forceinline__ unsigned short f2bf(float f) {
    unsigned u = __float_as_uint(f);
    u += 0x7FFFu + ((u >> 16) & 1u);          // RNE
    return (unsigned short)(u >> 16);
}

// merge two sorted pairs (a1<=a2), (b1<=b2) -> top-2 in (a1,a2). u32 lex keys.
__device__ __forceinline__ void merge2(unsigned &a1, unsigned &a2,
                                       unsigned b1, unsigned b2) {
    unsigned m1  = min(a1, b1);
    unsigned hi  = max(a1, b1);
    unsigned sel = (a1 < b1) ? a2 : b2;
    a2 = min(hi, sel);
    a1 = m1;
}

// ============ fused: emb -> enorm/enormB + bf16 swizzled ET3 ============
// 64-lane group per code row; enorm arithmetic IDENTICAL to rounds 1-4
// (float4 pairwise square-sum, 64-lane shuffle-xor tree).

__global__ __launch_bounds__(256)
void cvt_e_enorm(const float* __restrict__ emb, short* __restrict__ ET3,
                 float* __restrict__ enorm, float* __restrict__ enormB) {
    int t = threadIdx.x;
    int k = blockIdx.x * 4 + (t >> 6);
    int l = t & 63;
    float4 v = *(const float4*)(emb + (size_t)k * D_ + l * 4);
    float sum = v.x*v.x + v.y*v.y + v.z*v.z + v.w*v.w;
    for (int m = 1; m < 64; m <<= 1) sum += __shfl_xor(sum, m, 64);
    if (l == 0) { enorm[k] = sum; enormB[k] = sum + BIAS_; }
    // bf16 store: element e = 4l.. ; dcb = l>>4, chunk c = (l>>1)&7, half = l&1
    int dcb  = l >> 4;
    int c    = (l >> 1) & 7;
    int half = l & 1;
    bf16x4 o;
    o[0] = (short)f2bf(v.x); o[1] = (short)f2bf(v.y);
    o[2] = (short)f2bf(v.z); o[3] = (short)f2bf(v.w);
    *(bf16x4*)(ET3 + ((size_t)dcb * K_ + k) * 64 + ((c ^ (k & 7)) * 8) + half * 4) = o;
}

// ============ fused: z -> zpart chunks + bf16 swizzled ZT3 ============
// Per-chunk sums use the same sequential `sum += v*v` over dd=0..15 as the
// verified zpart_kernel; chunk dc = dcb*4+c2 matches the old layout exactly.

__global__ __launch_bounds__(256)
void zpart_cvtz(const float* __restrict__ z, float* __restrict__ zpart,
                short* __restrict__ ZT3) {
    int bx  = blockIdx.x;           // dcb*64 + stile
    int dcb = bx >> 6;
    int st  = bx & 63;
    int t   = threadIdx.x;
    int n   = st * 256 + t;
    int b   = n >> 10;
    int s   = n & 1023;
    const float* zb = z + (size_t)b * ZB + (size_t)(dcb * 64) * SP + s;
    short* dst = ZT3 + ((size_t)dcb * N_TOT + n) * 64;
    int sw = n & 7;
#pragma unroll
    for (int c2 = 0; c2 < 4; ++c2) {
        float vv[16];
#pragma unroll
        for (int dd = 0; dd < 16; ++dd)
            vv[dd] = zb[(size_t)(c2 * 16 + dd) * SP];
        float sum = 0.f;
#pragma unroll
        for (int dd = 0; dd < 16; ++dd) {
            float v = vv[dd];
            sum += v * v;
        }
        zpart[(size_t)(dcb * 4 + c2) * N_TOT + n] = sum;
        bf16x8 o0, o1;
#pragma unroll
        for (int j = 0; j < 8; ++j) { o0[j] = (short)f2bf(vv[j]);
                                      o1[j] = (short)f2bf(vv[8 + j]); }
        *(bf16x8*)(dst + (((c2 * 2)     ^ sw) * 8)) = o0;
        *(bf16x8*)(dst + (((c2 * 2 + 1) ^ sw) * 8)) = o1;
    }
}

// znorm: 16-chunk ordered sum (identical to rounds 1-4) + wl_cnt zero
__global__ __launch_bounds__(256)
void znorm_kernel2(const float* __restrict__ zpart, float* __restrict__ znorm,
                   int* __restrict__ wl_cnt) {
    int n = blockIdx.x * 256 + threadIdx.x;
    float sum = 0.f;
#pragma unroll
    for (int dc = 0; dc < 16; ++dc) sum += zpart[(size_t)dc * N_TOT + n];
    znorm[n] = sum;
    if (n == 0) *wl_cnt = 0;
}

// ======================= MFMA GEMM + packed-key top-2 (unchanged) =======================

__global__ __launch_bounds__(256, 4)
void mfma_argmin2(const short* __restrict__ ET3, const short* __restrict__ ZT3,
                  const float* __restrict__ enormB, uint2* __restrict__ pv) {
    __shared__ char smem[32768];                // As 16KB | Bs 16KB
    const int t    = threadIdx.x;
    const int wid  = t >> 6, lane = t & 63;
    const int quad = lane >> 4, l16 = lane & 15;
    const int wm   = wid >> 1, wn = wid & 1;
    const int stripe = blockIdx.x >> 7;
    const int n0     = (blockIdx.x & 127) * 128;
    const int swz    = (l16 & 7);

    unsigned r1[4], r2[4];
#pragma unroll
    for (int fj = 0; fj < 4; ++fj) { r1[fj] = 0xFFFFFFFFu; r2[fj] = 0xFFFFFFFFu; }

#pragma unroll 1
    for (int cc = 0; cc < 8; ++cc) {
        const int c0 = stripe * 1024 + cc * 128;
        f32x4 acc[4][4];
#pragma unroll
        for (int fi = 0; fi < 4; ++fi)
#pragma unroll
            for (int fj = 0; fj < 4; ++fj) acc[fi][fj] = (f32x4){0.f, 0.f, 0.f, 0.f};

#pragma unroll 1
        for (int dcb = 0; dcb < 4; ++dcb) {
            __syncthreads();
            const char* gA = (const char*)ET3 + ((size_t)dcb * K_    + c0) * 128;
            const char* gB = (const char*)ZT3 + ((size_t)dcb * N_TOT + n0) * 128;
#pragma unroll
            for (int j = 0; j < 4; ++j) {
                int off = j * 4096 + t * 16;
                GLOAD_LDS16(gA + off, smem + off);
                GLOAD_LDS16(gB + off, smem + 16384 + off);
            }
            __syncthreads();
#pragma unroll
            for (int dc2 = 0; dc2 < 2; ++dc2) {
                bf16x8 af[4], bfv[4];
                const int ch = ((dc2 * 4 + quad) ^ swz) * 16;
#pragma unroll
                for (int fi = 0; fi < 4; ++fi)
                    af[fi] = *(const bf16x8*)(smem + (wm*64 + fi*16 + l16)*128 + ch);
#pragma unroll
                for (int fj = 0; fj < 4; ++fj)
                    bfv[fj] = *(const bf16x8*)(smem + 16384 + (wn*64 + fj*16 + l16)*128 + ch);
#pragma unroll
                for (int fi = 0; fi < 4; ++fi)
#pragma unroll
                    for (int fj = 0; fj < 4; ++fj)
                        acc[fi][fj] = __builtin_amdgcn_mfma_f32_16x16x32_bf16(
                            af[fi], bfv[fj], acc[fi][fj], 0, 0, 0);
            }
        }

        float ekv[4][4];
#pragma unroll
        for (int fi = 0; fi < 4; ++fi) {
            float4 e4 = *(const float4*)(enormB + c0 + wm*64 + fi*16 + quad*4);
            ekv[fi][0]=e4.x; ekv[fi][1]=e4.y; ekv[fi][2]=e4.z; ekv[fi][3]=e4.w;
        }
#pragma unroll
        for (int fj = 0; fj < 4; ++fj) {
#pragma unroll
            for (int fi = 0; fi < 4; ++fi) {
                const unsigned cb = (unsigned)(c0 + wm*64 + fi*16 + quad*4);
                unsigned k0, k1, k2, k3;
                {
                    float s0 = fmaf(-2.f, acc[fi][fj].x, ekv[fi][0]);
                    float s1 = fmaf(-2.f, acc[fi][fj].y, ekv[fi][1]);
                    float s2 = fmaf(-2.f, acc[fi][fj].z, ekv[fi][2]);
                    float s3 = fmaf(-2.f, acc[fi][fj].w, ekv[fi][3]);
                    k0 = (__float_as_uint(s0) & 0xFFFFE000u) | (cb + 0u);
                    k1 = (__float_as_uint(s1) & 0xFFFFE000u) | (cb + 1u);
                    k2 = (__float_as_uint(s2) & 0xFFFFE000u) | (cb + 2u);
                    k3 = (__float_as_uint(s3) & 0xFFFFE000u) | (cb + 3u);
                }
                unsigned lo1 = min(k0, k1), hi1 = max(k0, k1);
                unsigned lo2 = min(k2, k3), hi2 = max(k2, k3);
                merge2(lo1, hi1, lo2, hi2);
                merge2(r1[fj], r2[fj], lo1, hi1);
            }
        }
    }

#pragma unroll
    for (int fj = 0; fj < 4; ++fj) {
        unsigned a1 = r1[fj], a2 = r2[fj];
#pragma unroll
        for (int m = 16; m <= 32; m <<= 1) {
            unsigned b1 = __shfl_xor(a1, m, 64);
            unsigned b2 = __shfl_xor(a2, m, 64);
            merge2(a1, a2, b1, b2);
        }
        if (quad == 0) {
            int n = n0 + wn*64 + fj*16 + l16;
            pv[(size_t)(stripe * 2 + wm) * N_TOT + n] = make_uint2(a1, a2);
        }
    }
}

// ======================= phase A: window classify + compact =======================

__global__ __launch_bounds__(256)
void reduce_phaseA(const uint2* __restrict__ pv, int* __restrict__ fidx,
                   float* __restrict__ out_idx, int* __restrict__ wl,
                   int* __restrict__ wl_cnt, float* __restrict__ out_loss) {
    int n = blockIdx.x * 256 + threadIdx.x;
    if (n == 0) *out_loss = 0.f;               // before output_kernel's atomicAdd
    uint2 pp[16];
    unsigned mn = 0xFFFFFFFFu;
#pragma unroll
    for (int g = 0; g < 16; ++g) {
        pp[g] = pv[(size_t)g * N_TOT + n];
        mn = min(mn, pp[g].x);
    }
    float smin  = __uint_as_float(mn & 0xFFFFE000u);
    unsigned th = __float_as_uint(smin + DELTA_) | 8191u;
    int cnt = 0;
#pragma unroll
    for (int g = 0; g < 16; ++g) {
        cnt += (pp[g].x <= th) ? 1 : 0;
        cnt += (pp[g].y <= th) ? 1 : 0;
    }
    if (cnt > 1) {
        int slot = atomicAdd(wl_cnt, 1);
        wl[slot] = n;
    } else {
        int c = (int)(mn & 8191u);
        fidx[n] = c;
        out_idx[n] = (float)c;
    }
}

// ======================= phase B: one wave per recheck row (unchanged) =======================

__global__ __launch_bounds__(256)
void recheck_kernel(const uint2* __restrict__ pv, const float* __restrict__ znorm,
                    const float* __restrict__ enorm, const float* __restrict__ z,
                    const float* __restrict__ emb, const int* __restrict__ wl,
                    const int* __restrict__ wl_cnt, int* __restrict__ fidx,
                    float* __restrict__ out_idx) {
    __shared__ float zrow[4][256];
    const int lane = threadIdx.x & 63;
    const int wslot = threadIdx.x >> 6;
    const int gwave = (blockIdx.x * 256 + threadIdx.x) >> 6;
    const int nwaves = (gridDim.x * 256) >> 6;
    const int total = *wl_cnt;

    for (int i = gwave; i < total; i += nwaves) {
        int n = wl[i];
        unsigned key = 0xFFFFFFFFu;
        if (lane < 32) {
            uint2 p = pv[(size_t)(lane & 15) * N_TOT + n];
            key = (lane < 16) ? p.x : p.y;
        }
        unsigned mn = key;
#pragma unroll
        for (int m = 1; m < 64; m <<= 1) mn = min(mn, __shfl_xor(mn, m, 64));
        float smin  = __uint_as_float(mn & 0xFFFFE000u);
        unsigned th = __float_as_uint(smin + DELTA_) | 8191u;

        const int b = n >> 10, sp = n & 1023;
        const float* zr = z + (size_t)b * ZB + sp;
#pragma unroll
        for (int j = 0; j < 4; ++j)
            zrow[wslot][lane + j * 64] = zr[(size_t)(lane + j * 64) * SP];
        float zn = znorm[n];

        unsigned lexlo = 0xFFFFFFFFu, lexhi = 0xFFFFFFFFu;
        if (key <= th) {
            int c = (int)(key & 8191u);
            const float* er = emb + (size_t)c * D_;
            float dot = 0.f;
#pragma unroll 8
            for (int d = 0; d < D_; ++d)
                dot = fmaf(zrow[wslot][d], er[d], dot);
            float s = (zn + enorm[c]) - 2.f * dot;
            unsigned sb = __float_as_uint(s);
            lexhi = sb >> 19;
            lexlo = (sb << 13) | (unsigned)c;
        }
#pragma unroll
        for (int m = 1; m < 64; m <<= 1) {
            unsigned olo = __shfl_xor(lexlo, m, 64);
            unsigned ohi = __shfl_xor(lexhi, m, 64);
            if (ohi < lexhi || (ohi == lexhi && olo < lexlo)) { lexhi = ohi; lexlo = olo; }
        }
        if (lane == 0) {
            int c = (int)(lexlo & 8191u);
            fidx[n] = c;
            out_idx[n] = (float)c;
        }
    }
}

// ======================= output / loss (unchanged) =======================

__global__ __launch_bounds__(256)
void output_kernel2(const float* __restrict__ z, const float* __restrict__ emb,
                    const int* __restrict__ fidx, float* __restrict__ out,
                    float* __restrict__ loss) {
    __shared__ float eL[32][257];
    __shared__ int   fid[32];
    __shared__ float red[4];
    const int nb = blockIdx.x;      // 0..511
    const int n0 = nb * 32;
    const int b  = n0 >> 10;
    const int s0 = n0 & 1023;
    const int t  = threadIdx.x;
    if (t < 32) fid[t] = fidx[n0 + t];
    __syncthreads();
#pragma unroll
    for (int i = 0; i < 8; ++i) {
        int p = t + i * 256;
        int row = p >> 6, q = p & 63;
        float4 v = *(const float4*)(emb + (size_t)fid[row] * D_ + q * 4);
        eL[row][q*4+0] = v.x; eL[row][q*4+1] = v.y;
        eL[row][q*4+2] = v.z; eL[row][q*4+3] = v.w;
    }
    __syncthreads();
    const int sl = t & 31, dg = t >> 5;
    float lsum = 0.f;
#pragma unroll
    for (int i = 0; i < 32; ++i) {
        int d = dg * 32 + i;
        size_t off = ((size_t)(b * D_ + d)) * SP + s0 + sl;
        float zv = z[off];
        float q  = eL[sl][d];
        float diff = q - zv;
        out[off] = zv + diff;
        lsum += diff * diff;
    }
    for (int m = 1; m < 64; m <<= 1) lsum += __shfl_xor(lsum, m, 64);
    if ((t & 63) == 0) red[t >> 6] = lsum;
    __syncthreads();
    if (t == 0) {
        float tot = (red[0] + red[1] + red[2] + red[3])
                    * (1.25f / (float)(B_ * SP * D_));
        atomicAdd(loss, tot);
    }
}

// ======================= fallback path (round-1 fp32, proven) =======================
#define MT 128
#define CT 128
#define DT 32
#define NSTRIPE 8
#define CPS (K_/NSTRIPE)
#define ES (CT+4)

__global__ __launch_bounds__(256)
void enorm_kernel(const float* __restrict__ emb, float* __restrict__ enorm,
                  float* __restrict__ enormB) {
    int t = threadIdx.x;
    int k = blockIdx.x * 4 + (t >> 6);
    int l = t & 63;
    float4 v = *(const float4*)(emb + (size_t)k * D_ + l * 4);
    float sum = v.x*v.x + v.y*v.y + v.z*v.z + v.w*v.w;
    for (int m = 1; m < 64; m <<= 1) sum += __shfl_xor(sum, m, 64);
    if (l == 0) { enorm[k] = sum; enormB[k] = sum + BIAS_; }
}

__global__ __launch_bounds__(256)
void zpart_kernel(const float* __restrict__ z, float* __restrict__ zpart) {
    int bx = blockIdx.x;
    int b  = bx >> 4;
    int dc = bx & 15;
    int t  = threadIdx.x;
#pragma unroll
    for (int i = 0; i < 4; ++i) {
        int s = t + i * 256;
        float sum = 0.f;
#pragma unroll
        for (int dd = 0; dd < 16; ++dd) {
            float v = z[(size_t)b * ZB + (size_t)(dc * 16 + dd) * SP + s];
            sum += v * v;
        }
        zpart[(size_t)dc * N_TOT + b * SP + s] = sum;
    }
}

__global__ __launch_bounds__(256)
void znorm_kernel(const float* __restrict__ zpart, float* __restrict__ znorm) {
    int n = blockIdx.x * 256 + threadIdx.x;
    float sum = 0.f;
#pragma unroll
    for (int dc = 0; dc < 16; ++dc) sum += zpart[(size_t)dc * N_TOT + n];
    znorm[n] = sum;
}

__global__ __launch_bounds__(256)
void gemm_argmin(const float* __restrict__ z, const float* __restrict__ emb,
                 const float* __restrict__ enorm, const float* __restrict__ znorm,
                 float* __restrict__ pvals, int* __restrict__ pidx) {
    __shared__ float zsm[DT][MT];
    __shared__ float esm[DT][ES];
    const int t = threadIdx.x;
    const int bx = blockIdx.x;
    const int stripe = bx & (NSTRIPE - 1);
    const int rb = bx >> 3;
    const int n0 = rb * MT;
    const int b  = n0 / SP;
    const int s0 = n0 % SP;
    const float* zb = z + (size_t)b * ZB + s0;
    const int tc = t & 15;
    const int tr = t >> 4;
    float zn[8];
#pragma unroll
    for (int i = 0; i < 8; ++i) zn[i] = znorm[n0 + tr * 8 + i];
    float best[8]; int bidx[8];
#pragma unroll
    for (int i = 0; i < 8; ++i) { best[i] = 3.4e38f; bidx[i] = 0; }
    for (int cc = 0; cc < CPS / CT; ++cc) {
        const int c0 = stripe * CPS + cc * CT;
        float acc[8][8];
#pragma unroll
        for (int i = 0; i < 8; ++i)
#pragma unroll
            for (int j = 0; j < 8; ++j) acc[i][j] = 0.f;
        for (int dc = 0; dc < D_ / DT; ++dc) {
            const int d0 = dc * DT;
            __syncthreads();
#pragma unroll
            for (int i = 0; i < 4; ++i) {
                int p  = t + i * 256;
                int d  = p >> 5;
                int rq = p & 31;
                float4 v = *(const float4*)(zb + (size_t)(d0 + d) * SP + rq * 4);
                *(float4*)&zsm[d][rq * 4] = v;
            }
#pragma unroll
            for (int i = 0; i < 4; ++i) {
                int p  = t + i * 256;
                int c  = p >> 3;
                int dq = p & 7;
                float4 v = *(const float4*)(emb + (size_t)(c0 + c) * D_ + d0 + dq * 4);
                esm[dq * 4 + 0][c] = v.x;
                esm[dq * 4 + 1][c] = v.y;
                esm[dq * 4 + 2][c] = v.z;
                esm[dq * 4 + 3][c] = v.w;
            }
            __syncthreads();
#pragma unroll 8
            for (int d = 0; d < DT; ++d) {
                float zr[8], ec[8];
                *(float4*)&zr[0] = *(const float4*)&zsm[d][tr * 8];
                *(float4*)&zr[4] = *(const float4*)&zsm[d][tr * 8 + 4];
                *(float4*)&ec[0] = *(const float4*)&esm[d][tc * 8];
                *(float4*)&ec[4] = *(const float4*)&esm[d][tc * 8 + 4];
#pragma unroll
                for (int i = 0; i < 8; ++i)
#pragma unroll
                    for (int j = 0; j < 8; ++j)
                        acc[i][j] = fmaf(zr[i], ec[j], acc[i][j]);
            }
        }
        float ek[8];
#pragma unroll
        for (int j = 0; j < 8; ++j) ek[j] = enorm[c0 + tc * 8 + j];
#pragma unroll
        for (int i = 0; i < 8; ++i) {
#pragma unroll
            for (int j = 0; j < 8; ++j) {
                float s = (zn[i] + ek[j]) - 2.0f * acc[i][j];
                int code = c0 + tc * 8 + j;
                if (s < best[i] || (s == best[i] && code < bidx[i])) {
                    best[i] = s; bidx[i] = code;
                }
            }
        }
    }
#pragma unroll
    for (int i = 0; i < 8; ++i) {
        float v = best[i]; int ix = bidx[i];
        for (int m = 1; m < 16; m <<= 1) {
            float ov = __shfl_xor(v, m, 64);
            int   oi = __shfl_xor(ix, m, 64);
            if (ov < v || (ov == v && oi < ix)) { v = ov; ix = oi; }
        }
        if (tc == 0) {
            int n = n0 + tr * 8 + i;
            pvals[n * NSTRIPE + stripe] = v;
            pidx [n * NSTRIPE + stripe] = ix;
        }
    }
}

__global__ __launch_bounds__(256)
void reduce_rows(const float* __restrict__ pvals, const int* __restrict__ pidx,
                 int* __restrict__ fidx, float* __restrict__ out_idx) {
    int n = blockIdx.x * 256 + threadIdx.x;
    float bv = 3.4e38f; int bi = 0;
#pragma unroll
    for (int s = 0; s < NSTRIPE; ++s) {
        float v = pvals[n * NSTRIPE + s];
        int  ix = pidx [n * NSTRIPE + s];
        if (v < bv || (v == bv && ix < bi)) { bv = v; bi = ix; }
    }
    fidx[n] = bi;
    out_idx[n] = (float)bi;
}

// ======================= launch =======================
// fast ws layout (floats):
//   enorm [0,8192) enormB [8192,16384) znorm [16384,32768) fidx [32768,49152)
//   wl_cnt [49152] (pad to 49216)   wl [49216,65600)  (pad to 65664)
//   pv    [65664,589952)  (16 groups x 16384 uint2; zpart aliases its head)
//   ET3   [589952,1638528) (bf16)   ZT3 [1638528,3735680) (bf16)
// NEED = 3,735,680*4 = 14,942,720 B (proven grant)

extern "C" void kernel_launch(void* const* d_in, const int* in_sizes, int n_in,
                              void* d_out, int out_size, void* d_ws, size_t ws_size,
                              hipStream_t stream) {
    const float* z   = (const float*)d_in[0];
    const float* emb = (const float*)d_in[1];
    float* out = (float*)d_out;
    float* w   = (float*)d_ws;

    float* enorm  = w;
    float* enormB = w + 8192;
    float* znorm  = w + 16384;
    int*   fidx   = (int*)(w + 32768);

    float* out0     = out;
    float* out_loss = out + (size_t)B_ * D_ * SP;
    float* out_idx  = out_loss + 1;

    const size_t NEED = 3735680ULL * 4ULL;
    if (ws_size >= NEED) {
        int*   wl_cnt = (int*)(w + 49152);
        int*   wl     = (int*)(w + 49216);
        uint2* pv     = (uint2*)(w + 65664);
        float* zpart  = w + 65664;             // aliases pv (dead before pv written)
        short* ET3    = (short*)(w + 589952);
        short* ZT3    = (short*)(w + 1638528);

        cvt_e_enorm<<<K_ / 4, 256, 0, stream>>>(emb, ET3, enorm, enormB);
        zpart_cvtz<<<256, 256, 0, stream>>>(z, zpart, ZT3);
        znorm_kernel2<<<N_TOT / 256, 256, 0, stream>>>(zpart, znorm, wl_cnt);
        mfma_argmin2<<<1024, 256, 0, stream>>>(ET3, ZT3, enormB, pv);
        reduce_phaseA<<<N_TOT / 256, 256, 0, stream>>>(pv, fidx, out_idx, wl,
                                                       wl_cnt, out_loss);
        recheck_kernel<<<256, 256, 0, stream>>>(pv, znorm, enorm, z, emb,
                                                wl, wl_cnt, fidx, out_idx);
        output_kernel2<<<N_TOT / 32, 256, 0, stream>>>(z, emb, fidx, out0, out_loss);
    } else {
        float* zpart = w + 32768;              // [32768, 294912)
        float* znF   = w + 294912;             // [294912, 311296)
        float* pvals = w + 311296;             // [311296, 442368)
        int*   pidxF = (int*)(w + 442368);     // [442368, 573440)
        int*   fidxF = (int*)(w + 573440);
        fidx = fidxF;
        enorm_kernel<<<K_ / 4, 256, 0, stream>>>(emb, enorm, enormB);
        zpart_kernel<<<B_ * 16, 256, 0, stream>>>(z, zpart);
        znorm_kernel<<<N_TOT / 256, 256, 0, stream>>>(zpart, znF);
        gemm_argmin<<<(N_TOT / MT) * NSTRIPE, 256, 0, stream>>>(z, emb, enorm, znF,
                                                                pvals, pidxF);
        reduce_rows<<<N_TOT / 256, 256, 0, stream>>>(pvals, pidxF, fidx, out_idx);
        hipMemsetAsync(out_loss, 0, sizeof(float), stream);
        output_kernel2<<<N_TOT / 32, 256, 0, stream>>>(z, emb, fidx, out0, out_loss);
    }
}